// Round 11
// baseline (260.717 us; speedup 1.0000x reference)
//
#include <hip/hip_runtime.h>
#include <math.h>

// StickBreakingVAE forward, bf16-MFMA, 8-wave blocks, XCD swizzle.
// GEMM1 (AF32): A staged as RAW F32 via global_load_lds (32KB tile, 32B-pair
// XOR swizzle via pre-swizzled source), f32->bf16 cvt in the LDS->fragment
// path. K-tail clamped PER 16B GRANULE (r10 bug: clamp was 16-f32-coarse,
// corrupting x[772..783]; now clampA = Kreal-4). Pad granules load garbage
// that multiplies zero-padded W rows -> exact 0. No cast_x kernel.
// Other GEMMs: proven r8 single-buffered gll structure.
// B=32768, D=784, H=500, K=50.

typedef __bf16 bf16x8 __attribute__((ext_vector_type(8)));
typedef float f32x4 __attribute__((ext_vector_type(4)));

#define BATCH 32768
#define BM 128
#define BN 128
#define BK 64
#define NTHR 512

__device__ __forceinline__ unsigned short bf16_bits(float f) {
    __bf16 b = (__bf16)f;
    return __builtin_bit_cast(unsigned short, b);
}

__device__ __forceinline__ void gll16(const void* src, void* ldsdst) {
    __builtin_amdgcn_global_load_lds(
        (const __attribute__((address_space(1))) unsigned int*)src,
        (__attribute__((address_space(3))) unsigned int*)ldsdst,
        16, 0, 0);
}

// MODE 0: relu -> bf16 C [ldc]; MODE 1: softplus -> alpha/beta f32 compact;
// MODE 2: sigmoid -> f32 C [B,Nreal] masked.
// AF32: A is f32 [M][lda]; gll-staged raw f32, cvt at fragment read.
template<int MODE, bool AF32>
__global__ __launch_bounds__(NTHR, 4) void mfma_gemm(
    const void* __restrict__ Av,
    const unsigned short* __restrict__ Bt,  // [Npad][Kpad] bf16 (zero-padded)
    const float* __restrict__ bias,         // [Npad]
    void* __restrict__ Cv,
    int Kpad, int Kreal, int lda, int ldc, int Nreal, int nbx)
{
    // A tile: f32 (32KB) when AF32 else bf16 (16KB); B tile bf16 16KB
    __shared__ unsigned char AsRaw[AF32 ? (BM * BK * 4) : (BM * BK * 2)];
    __shared__ unsigned short Bs[BN * BK];

    // ---- chunked bijective XCD swizzle (T1, m204) ----
    const int nwg = gridDim.x;
    const int orig = blockIdx.x;
    const int q = nwg >> 3, r8 = nwg & 7;
    const int xcd = orig & 7;
    const int chunkbase = (xcd < r8) ? xcd * (q + 1) : r8 * (q + 1) + (xcd - r8) * q;
    const int wgid = chunkbase + (orig >> 3);
    const int bn = wgid % nbx;               // n fastest -> A-panel L2 reuse
    const size_t block_m = (size_t)(wgid / nbx) * BM;
    const int block_n = bn * BN;

    const int tid = threadIdx.x;
    const int l = tid & 63;
    const int wid = tid >> 6;                // 0..7
    const int wr = wid >> 2, wc = wid & 3;   // wave tile: 64 rows x 32 cols

    const int lr = l & 15;
    const int kh = l >> 4;

    f32x4 acc[4][2] = {};

    auto issueB = [&](int k0) {
        #pragma unroll
        for (int i = 0; i < 2; ++i) {
            int chunk = wid * 2 + i;          // 16 chunks x 64 granules(16B)
            int gid = chunk * 64 + l;         // granule 0..1023
            int r = gid >> 3;                 // B tile row (n-index) 0..127
            int kgs = (gid & 7) ^ (r & 7);    // pre-swizzled source granule
            gll16(Bt + (size_t)(block_n + r) * Kpad + k0 + kgs * 8,
                  (unsigned short*)Bs + chunk * 512);
        }
    };

    auto issueA = [&](int k0) {
        if constexpr (AF32) {
            // f32 tile: 128 rows x 64 f32 = 2048 granules(16B); 32B-pair swizzle.
            const float* Af = (const float*)Av;
            const int clampA = Kreal - 4;     // 780: largest in-bounds 16B granule
            #pragma unroll
            for (int i = 0; i < 4; ++i) {
                int chunk = wid * 4 + i;      // 32 chunks x 64 granules
                int gid = chunk * 64 + l;     // granule 0..2047
                int r = gid >> 4;             // row 0..127 (16 granules/row)
                int gcol = gid & 15;
                int p = gcol >> 1, half = gcol & 1;
                int koff = (p ^ (r & 7)) * 8 + half * 4;   // f32 k-offset in tile
                int gk = k0 + koff;
                int gkc = (gk <= clampA) ? gk : clampA;    // per-granule tail clamp
                gll16(Af + (block_m + r) * (size_t)lda + gkc,
                      AsRaw + chunk * 1024);
            }
        } else {
            const unsigned short* Ab = (const unsigned short*)Av;
            #pragma unroll
            for (int i = 0; i < 2; ++i) {
                int chunk = wid * 2 + i;
                int gid = chunk * 64 + l;
                int r = gid >> 3;
                int kgs = (gid & 7) ^ (r & 7);
                gll16(Ab + (block_m + r) * (size_t)lda + k0 + kgs * 8,
                      (unsigned short*)AsRaw + chunk * 512);
            }
        }
    };

    auto compute = [&]() {
        #pragma unroll
        for (int s = 0; s < 2; ++s) {
            bf16x8 af[4], bf[2];
            #pragma unroll
            for (int mi = 0; mi < 4; ++mi) {
                int row = wr * 64 + mi * 16 + lr;
                int j = (s * 4 + kh);
                if constexpr (AF32) {
                    // f32 row stride 256B; 32B pair at (j ^ (row&7))
                    const float* fp = (const float*)(AsRaw + row * 256 +
                                                     ((j ^ (row & 7)) * 32));
                    float4 q0 = ((const float4*)fp)[0];
                    float4 q1 = ((const float4*)fp)[1];
                    union { __bf16 b[8]; bf16x8 v; } cv;
                    cv.b[0] = (__bf16)q0.x; cv.b[1] = (__bf16)q0.y;
                    cv.b[2] = (__bf16)q0.z; cv.b[3] = (__bf16)q0.w;
                    cv.b[4] = (__bf16)q1.x; cv.b[5] = (__bf16)q1.y;
                    cv.b[6] = (__bf16)q1.z; cv.b[7] = (__bf16)q1.w;
                    af[mi] = cv.v;
                } else {
                    int g = j ^ (row & 7);
                    af[mi] = *(const bf16x8*)((const unsigned short*)AsRaw +
                                              row * 64 + g * 8);
                }
            }
            #pragma unroll
            for (int ni = 0; ni < 2; ++ni) {
                int row = wc * 32 + ni * 16 + lr;
                int g = (s * 4 + kh) ^ (row & 7);
                bf[ni] = *(const bf16x8*)((const unsigned short*)Bs + row * 64 + g * 8);
            }
            #pragma unroll
            for (int mi = 0; mi < 4; ++mi)
                #pragma unroll
                for (int ni = 0; ni < 2; ++ni)
                    acc[mi][ni] = __builtin_amdgcn_mfma_f32_16x16x32_bf16(
                        af[mi], bf[ni], acc[mi][ni], 0, 0, 0);
        }
    };

    // single-buffered gll loop (proven structure; compiler handles waits)
    for (int k0 = 0; k0 < Kpad; k0 += BK) {
        issueB(k0);
        issueA(k0);
        __syncthreads();
        compute();
        __syncthreads();
    }

    // epilogue: C/D layout col=lane&15, row=(lane>>4)*4+j
    const int rg = (l >> 4) * 4;
    #pragma unroll
    for (int mi = 0; mi < 4; ++mi) {
        #pragma unroll
        for (int ni = 0; ni < 2; ++ni) {
            int gn = block_n + wc * 32 + ni * 16 + lr;
            float bs = bias[gn];
            #pragma unroll
            for (int j = 0; j < 4; ++j) {
                long gm = block_m + wr * 64 + mi * 16 + rg + j;
                float z = acc[mi][ni][j] + bs;
                if (MODE == 0) {
                    z = fmaxf(z, 0.f);
                    ((unsigned short*)Cv)[gm * ldc + gn] = bf16_bits(z);
                } else if (MODE == 1) {
                    z = (z > 0.f) ? z + __logf(1.f + __expf(-z))
                                  : __logf(1.f + __expf(z));
                    float* out = (float*)Cv;
                    if (gn < 50)       out[gm * 50 + gn] = z;
                    else if (gn < 100) out[(size_t)BATCH * 50 + gm * 50 + (gn - 50)] = z;
                } else {
                    if (gn < Nreal) {
                        z = __fdividef(1.f, 1.f + __expf(-z));   // single-sided sigmoid
                        ((float*)Cv)[gm * Nreal + gn] = z;
                    }
                }
            }
        }
    }
}

// weight [Kr][Nr] f32 -> [Npad][Kpad] bf16 transposed, bias padded
__global__ __launch_bounds__(256) void prep_bt(
    const float* __restrict__ W, const float* __restrict__ bias,
    unsigned short* __restrict__ Bt, float* __restrict__ bpad,
    int Kr, int Nr, int Kpad, int Npad)
{
    int idx = blockIdx.x * 256 + threadIdx.x;
    if (idx >= Npad * Kpad) return;
    int n = idx / Kpad, k = idx - n * Kpad;
    float v = (n < Nr && k < Kr) ? W[(size_t)k * Nr + n] : 0.f;
    Bt[idx] = bf16_bits(v);
    if (k == 0) bpad[n] = (n < Nr) ? bias[n] : 0.f;
}

// [w_alpha | w_beta] -> [128][512] bf16 transposed
__global__ __launch_bounds__(256) void prep_wab(
    const float* __restrict__ Wa, const float* __restrict__ Wb,
    const float* __restrict__ ba, const float* __restrict__ bb,
    unsigned short* __restrict__ Bt, float* __restrict__ bpad)
{
    int idx = blockIdx.x * 256 + threadIdx.x;
    if (idx >= 128 * 512) return;
    int n = idx >> 9, k = idx & 511;
    float v = 0.f;
    if (k < 500) {
        if (n < 50)       v = Wa[(size_t)k * 50 + n];
        else if (n < 100) v = Wb[(size_t)k * 50 + (n - 50)];
    }
    Bt[idx] = bf16_bits(v);
    if (k == 0) bpad[n] = (n < 50) ? ba[n] : ((n < 100) ? bb[n - 50] : 0.f);
}

// Kumaraswamy sample + stick-breaking: one wave per row, shuffle prefix-product.
__global__ __launch_bounds__(256) void sample_pi(
    const float* __restrict__ u, const float* __restrict__ alpha,
    const float* __restrict__ beta, unsigned short* __restrict__ pib)
{
    int row = (blockIdx.x * 256 + threadIdx.x) >> 6;
    int lane = threadIdx.x & 63;
    size_t base = (size_t)row * 50;

    float v = 0.f, w = 1.f;
    if (lane < 50) {
        float a = alpha[base + lane];
        float b = beta[base + lane];
        float uu = u[base + lane];
        float t = exp2f(__fdividef(log2f(uu), b));          // u^(1/beta)
        v = exp2f(__fdividef(log2f(1.f - t), a));           // (1-t)^(1/alpha)
        w = 1.f - v;
    }
    float p = w;
    #pragma unroll
    for (int off = 1; off < 64; off <<= 1) {
        float t = __shfl_up(p, off, 64);
        if (lane >= off) p *= t;
    }
    float ex = __shfl_up(p, 1, 64);
    if (lane == 0) ex = 1.f;
    float pi = v * ex;
    pib[(size_t)row * 64 + lane] = (lane < 50) ? bf16_bits(pi) : (unsigned short)0;
}

extern "C" void kernel_launch(void* const* d_in, const int* in_sizes, int n_in,
                              void* d_out, int out_size, void* d_ws, size_t ws_size,
                              hipStream_t stream) {
    const float* x       = (const float*)d_in[0];
    const float* u       = (const float*)d_in[1];
    const float* enc_w1  = (const float*)d_in[2];
    const float* enc_b1  = (const float*)d_in[3];
    const float* w_alpha = (const float*)d_in[4];
    const float* b_alpha = (const float*)d_in[5];
    const float* w_beta  = (const float*)d_in[6];
    const float* b_beta  = (const float*)d_in[7];
    const float* dec_w1  = (const float*)d_in[8];
    const float* dec_b1  = (const float*)d_in[9];
    const float* dec_w2  = (const float*)d_in[10];
    const float* dec_b2  = (const float*)d_in[11];

    const int D = 784;

    float* out   = (float*)d_out;
    float* recon = out;                              // [B,784] f32
    float* alpha = out + (size_t)BATCH * D;          // [B,50]; beta at +B*50

    // workspace layout
    char* ws = (char*)d_ws;
    unsigned short* w1b  = (unsigned short*)(ws);             // 512*832*2
    unsigned short* wab  = (unsigned short*)(ws + 851968);    // 128*512*2
    unsigned short* dw1b = (unsigned short*)(ws + 983040);    // 512*64*2
    unsigned short* dw2b = (unsigned short*)(ws + 1048576);   // 896*512*2
    float* bias1  = (float*)(ws + 1966080);
    float* biasab = (float*)(ws + 1968128);
    float* biasd1 = (float*)(ws + 1970688);
    float* biasd2 = (float*)(ws + 1972736);
    unsigned short* h    = (unsigned short*)(ws + 2097152);   // [B][512] bf16
    unsigned short* pib  = (unsigned short*)(ws + 35651584);  // [B][64]  bf16
    unsigned short* hdb  = h;                                  // reuse h
    // peak ws = 39.85 MB

    // ---- prep weights ----
    prep_bt<<<dim3(512 * 832 / 256), 256, 0, stream>>>(
        enc_w1, enc_b1, w1b, bias1, 784, 500, 832, 512);
    prep_wab<<<dim3(256), 256, 0, stream>>>(w_alpha, w_beta, b_alpha, b_beta, wab, biasab);
    prep_bt<<<dim3(512 * 64 / 256), 256, 0, stream>>>(
        dec_w1, dec_b1, dw1b, biasd1, 50, 500, 64, 512);
    prep_bt<<<dim3(896 * 512 / 256), 256, 0, stream>>>(
        dec_w2, dec_b2, dw2b, biasd2, 500, 784, 512, 896);

    // ---- GEMM1: h = relu(x @ enc_w1 + b1), f32-A gll staging + frag cvt ----
    mfma_gemm<0, true><<<dim3((512 / BN) * (BATCH / BM)), NTHR, 0, stream>>>(
        x, w1b, bias1, h, 832, 784, 784, 512, 500, 512 / BN);

    // ---- GEMM2/3: [alpha|beta] = softplus(h @ wab + b) ----
    mfma_gemm<1, false><<<dim3(BATCH / BM), NTHR, 0, stream>>>(
        h, wab, biasab, alpha, 512, 512, 512, 0, 100, 1);

    // ---- sample: one wave per row ----
    sample_pi<<<dim3(BATCH * 64 / 256), 256, 0, stream>>>(
        u, alpha, alpha + (size_t)BATCH * 50, pib);

    // ---- GEMM4: hd = relu(pib @ dec_w1 + b) ----
    mfma_gemm<0, false><<<dim3((512 / BN) * (BATCH / BM)), NTHR, 0, stream>>>(
        pib, dw1b, biasd1, hdb, 64, 64, 64, 512, 500, 512 / BN);

    // ---- GEMM5: recon = sigmoid(hd @ dec_w2 + b) ----
    mfma_gemm<2, false><<<dim3((896 / BN) * (BATCH / BM)), NTHR, 0, stream>>>(
        hdb, dw2b, biasd2, recon, 512, 512, 512, 784, 784, 896 / BN);
}

// Round 12
// 158.091 us; speedup vs baseline: 1.6492x; 1.6492x over previous
//
#include <hip/hip_runtime.h>
#include <math.h>

// StickBreakingVAE forward, bf16-MFMA, 8-wave blocks, XCD swizzle.
// GEMM1 (AF32): A staged as RAW F32 via global_load_lds (32KB tile), 16B-GRANULE
// XOR swizzle (slot = c ^ (row&7), applied at gll source; r11's 32B-pair swizzle
// aliased banks mod 4 -> 4-way conflict, 6.6e7 SQ_LDS_BANK_CONFLICT). Fragment
// read: k-slot j = granules (2j)^r7 and ((2j)^r7)^1 -> 8 distinct bank slots per
// 8 rows = conflict-free (2-way, free per m136). f32->bf16 cvt at fragment read.
// K-tail clamped per granule (clampA=780; pad granules x zero W rows = 0).
// Other GEMMs: proven r8 single-buffered gll structure.
// B=32768, D=784, H=500, K=50.

typedef __bf16 bf16x8 __attribute__((ext_vector_type(8)));
typedef float f32x4 __attribute__((ext_vector_type(4)));

#define BATCH 32768
#define BM 128
#define BN 128
#define BK 64
#define NTHR 512

__device__ __forceinline__ unsigned short bf16_bits(float f) {
    __bf16 b = (__bf16)f;
    return __builtin_bit_cast(unsigned short, b);
}

__device__ __forceinline__ void gll16(const void* src, void* ldsdst) {
    __builtin_amdgcn_global_load_lds(
        (const __attribute__((address_space(1))) unsigned int*)src,
        (__attribute__((address_space(3))) unsigned int*)ldsdst,
        16, 0, 0);
}

// MODE 0: relu -> bf16 C [ldc]; MODE 1: softplus -> alpha/beta f32 compact;
// MODE 2: sigmoid -> f32 C [B,Nreal] masked.
// AF32: A is f32 [M][lda]; gll-staged raw f32, cvt at fragment read.
template<int MODE, bool AF32>
__global__ __launch_bounds__(NTHR, 4) void mfma_gemm(
    const void* __restrict__ Av,
    const unsigned short* __restrict__ Bt,  // [Npad][Kpad] bf16 (zero-padded)
    const float* __restrict__ bias,         // [Npad]
    void* __restrict__ Cv,
    int Kpad, int Kreal, int lda, int ldc, int Nreal, int nbx)
{
    // A tile: f32 (32KB) when AF32 else bf16 (16KB); B tile bf16 16KB
    __shared__ unsigned char AsRaw[AF32 ? (BM * BK * 4) : (BM * BK * 2)];
    __shared__ unsigned short Bs[BN * BK];

    // ---- chunked bijective XCD swizzle (T1, m204) ----
    const int nwg = gridDim.x;
    const int orig = blockIdx.x;
    const int q = nwg >> 3, r8 = nwg & 7;
    const int xcd = orig & 7;
    const int chunkbase = (xcd < r8) ? xcd * (q + 1) : r8 * (q + 1) + (xcd - r8) * q;
    const int wgid = chunkbase + (orig >> 3);
    const int bn = wgid % nbx;               // n fastest -> A-panel L2 reuse
    const size_t block_m = (size_t)(wgid / nbx) * BM;
    const int block_n = bn * BN;

    const int tid = threadIdx.x;
    const int l = tid & 63;
    const int wid = tid >> 6;                // 0..7
    const int wr = wid >> 2, wc = wid & 3;   // wave tile: 64 rows x 32 cols

    const int lr = l & 15;
    const int kh = l >> 4;

    f32x4 acc[4][2] = {};

    auto issueB = [&](int k0) {
        #pragma unroll
        for (int i = 0; i < 2; ++i) {
            int chunk = wid * 2 + i;          // 16 chunks x 64 granules(16B)
            int gid = chunk * 64 + l;         // granule 0..1023
            int r = gid >> 3;                 // B tile row (n-index) 0..127
            int kgs = (gid & 7) ^ (r & 7);    // pre-swizzled source granule
            gll16(Bt + (size_t)(block_n + r) * Kpad + k0 + kgs * 8,
                  (unsigned short*)Bs + chunk * 512);
        }
    };

    auto issueA = [&](int k0) {
        if constexpr (AF32) {
            // f32 tile: 128 rows x 16 granules(16B = 4 f32) = 2048 granules.
            // LDS slot gcol holds source granule c = gcol ^ (row&7).
            const float* Af = (const float*)Av;
            const int clampA = Kreal - 4;     // 780: largest in-bounds 16B granule
            #pragma unroll
            for (int i = 0; i < 4; ++i) {
                int chunk = wid * 4 + i;      // 32 chunks x 64 granules
                int gid = chunk * 64 + l;     // granule 0..2047
                int r = gid >> 4;             // row 0..127 (16 granules/row)
                int gcol = gid & 15;
                int koff = (gcol ^ (r & 7)) * 4;           // f32 k-offset in tile
                int gk = k0 + koff;
                int gkc = (gk <= clampA) ? gk : clampA;    // per-granule tail clamp
                gll16(Af + (block_m + r) * (size_t)lda + gkc,
                      AsRaw + chunk * 1024);
            }
        } else {
            const unsigned short* Ab = (const unsigned short*)Av;
            #pragma unroll
            for (int i = 0; i < 2; ++i) {
                int chunk = wid * 2 + i;
                int gid = chunk * 64 + l;
                int r = gid >> 3;
                int kgs = (gid & 7) ^ (r & 7);
                gll16(Ab + (block_m + r) * (size_t)lda + k0 + kgs * 8,
                      (unsigned short*)AsRaw + chunk * 512);
            }
        }
    };

    auto compute = [&]() {
        #pragma unroll
        for (int s = 0; s < 2; ++s) {
            bf16x8 af[4], bf[2];
            #pragma unroll
            for (int mi = 0; mi < 4; ++mi) {
                int row = wr * 64 + mi * 16 + lr;
                int j = (s * 4 + kh);
                if constexpr (AF32) {
                    // granule c=2j at slot (2j)^(row&7); c=2j+1 at slot ^1
                    int sl0 = (2 * j) ^ (row & 7);
                    const float* fp0 = (const float*)(AsRaw + row * 256 + sl0 * 16);
                    const float* fp1 = (const float*)(AsRaw + row * 256 + (sl0 ^ 1) * 16);
                    float4 q0 = *(const float4*)fp0;
                    float4 q1 = *(const float4*)fp1;
                    union { __bf16 b[8]; bf16x8 v; } cv;
                    cv.b[0] = (__bf16)q0.x; cv.b[1] = (__bf16)q0.y;
                    cv.b[2] = (__bf16)q0.z; cv.b[3] = (__bf16)q0.w;
                    cv.b[4] = (__bf16)q1.x; cv.b[5] = (__bf16)q1.y;
                    cv.b[6] = (__bf16)q1.z; cv.b[7] = (__bf16)q1.w;
                    af[mi] = cv.v;
                } else {
                    int g = j ^ (row & 7);
                    af[mi] = *(const bf16x8*)((const unsigned short*)AsRaw +
                                              row * 64 + g * 8);
                }
            }
            #pragma unroll
            for (int ni = 0; ni < 2; ++ni) {
                int row = wc * 32 + ni * 16 + lr;
                int g = (s * 4 + kh) ^ (row & 7);
                bf[ni] = *(const bf16x8*)((const unsigned short*)Bs + row * 64 + g * 8);
            }
            #pragma unroll
            for (int mi = 0; mi < 4; ++mi)
                #pragma unroll
                for (int ni = 0; ni < 2; ++ni)
                    acc[mi][ni] = __builtin_amdgcn_mfma_f32_16x16x32_bf16(
                        af[mi], bf[ni], acc[mi][ni], 0, 0, 0);
        }
    };

    // single-buffered gll loop (proven structure; compiler handles waits)
    for (int k0 = 0; k0 < Kpad; k0 += BK) {
        issueB(k0);
        issueA(k0);
        __syncthreads();
        compute();
        __syncthreads();
    }

    // epilogue: C/D layout col=lane&15, row=(lane>>4)*4+j
    const int rg = (l >> 4) * 4;
    #pragma unroll
    for (int mi = 0; mi < 4; ++mi) {
        #pragma unroll
        for (int ni = 0; ni < 2; ++ni) {
            int gn = block_n + wc * 32 + ni * 16 + lr;
            float bs = bias[gn];
            #pragma unroll
            for (int j = 0; j < 4; ++j) {
                long gm = block_m + wr * 64 + mi * 16 + rg + j;
                float z = acc[mi][ni][j] + bs;
                if (MODE == 0) {
                    z = fmaxf(z, 0.f);
                    ((unsigned short*)Cv)[gm * ldc + gn] = bf16_bits(z);
                } else if (MODE == 1) {
                    z = (z > 0.f) ? z + __logf(1.f + __expf(-z))
                                  : __logf(1.f + __expf(z));
                    float* out = (float*)Cv;
                    if (gn < 50)       out[gm * 50 + gn] = z;
                    else if (gn < 100) out[(size_t)BATCH * 50 + gm * 50 + (gn - 50)] = z;
                } else {
                    if (gn < Nreal) {
                        z = __fdividef(1.f, 1.f + __expf(-z));   // single-sided sigmoid
                        ((float*)Cv)[gm * Nreal + gn] = z;
                    }
                }
            }
        }
    }
}

// weight [Kr][Nr] f32 -> [Npad][Kpad] bf16 transposed, bias padded
__global__ __launch_bounds__(256) void prep_bt(
    const float* __restrict__ W, const float* __restrict__ bias,
    unsigned short* __restrict__ Bt, float* __restrict__ bpad,
    int Kr, int Nr, int Kpad, int Npad)
{
    int idx = blockIdx.x * 256 + threadIdx.x;
    if (idx >= Npad * Kpad) return;
    int n = idx / Kpad, k = idx - n * Kpad;
    float v = (n < Nr && k < Kr) ? W[(size_t)k * Nr + n] : 0.f;
    Bt[idx] = bf16_bits(v);
    if (k == 0) bpad[n] = (n < Nr) ? bias[n] : 0.f;
}

// [w_alpha | w_beta] -> [128][512] bf16 transposed
__global__ __launch_bounds__(256) void prep_wab(
    const float* __restrict__ Wa, const float* __restrict__ Wb,
    const float* __restrict__ ba, const float* __restrict__ bb,
    unsigned short* __restrict__ Bt, float* __restrict__ bpad)
{
    int idx = blockIdx.x * 256 + threadIdx.x;
    if (idx >= 128 * 512) return;
    int n = idx >> 9, k = idx & 511;
    float v = 0.f;
    if (k < 500) {
        if (n < 50)       v = Wa[(size_t)k * 50 + n];
        else if (n < 100) v = Wb[(size_t)k * 50 + (n - 50)];
    }
    Bt[idx] = bf16_bits(v);
    if (k == 0) bpad[n] = (n < 50) ? ba[n] : ((n < 100) ? bb[n - 50] : 0.f);
}

// Kumaraswamy sample + stick-breaking: one wave per row, shuffle prefix-product.
__global__ __launch_bounds__(256) void sample_pi(
    const float* __restrict__ u, const float* __restrict__ alpha,
    const float* __restrict__ beta, unsigned short* __restrict__ pib)
{
    int row = (blockIdx.x * 256 + threadIdx.x) >> 6;
    int lane = threadIdx.x & 63;
    size_t base = (size_t)row * 50;

    float v = 0.f, w = 1.f;
    if (lane < 50) {
        float a = alpha[base + lane];
        float b = beta[base + lane];
        float uu = u[base + lane];
        float t = exp2f(__fdividef(log2f(uu), b));          // u^(1/beta)
        v = exp2f(__fdividef(log2f(1.f - t), a));           // (1-t)^(1/alpha)
        w = 1.f - v;
    }
    float p = w;
    #pragma unroll
    for (int off = 1; off < 64; off <<= 1) {
        float t = __shfl_up(p, off, 64);
        if (lane >= off) p *= t;
    }
    float ex = __shfl_up(p, 1, 64);
    if (lane == 0) ex = 1.f;
    float pi = v * ex;
    pib[(size_t)row * 64 + lane] = (lane < 50) ? bf16_bits(pi) : (unsigned short)0;
}

extern "C" void kernel_launch(void* const* d_in, const int* in_sizes, int n_in,
                              void* d_out, int out_size, void* d_ws, size_t ws_size,
                              hipStream_t stream) {
    const float* x       = (const float*)d_in[0];
    const float* u       = (const float*)d_in[1];
    const float* enc_w1  = (const float*)d_in[2];
    const float* enc_b1  = (const float*)d_in[3];
    const float* w_alpha = (const float*)d_in[4];
    const float* b_alpha = (const float*)d_in[5];
    const float* w_beta  = (const float*)d_in[6];
    const float* b_beta  = (const float*)d_in[7];
    const float* dec_w1  = (const float*)d_in[8];
    const float* dec_b1  = (const float*)d_in[9];
    const float* dec_w2  = (const float*)d_in[10];
    const float* dec_b2  = (const float*)d_in[11];

    const int D = 784;

    float* out   = (float*)d_out;
    float* recon = out;                              // [B,784] f32
    float* alpha = out + (size_t)BATCH * D;          // [B,50]; beta at +B*50

    // workspace layout
    char* ws = (char*)d_ws;
    unsigned short* w1b  = (unsigned short*)(ws);             // 512*832*2
    unsigned short* wab  = (unsigned short*)(ws + 851968);    // 128*512*2
    unsigned short* dw1b = (unsigned short*)(ws + 983040);    // 512*64*2
    unsigned short* dw2b = (unsigned short*)(ws + 1048576);   // 896*512*2
    float* bias1  = (float*)(ws + 1966080);
    float* biasab = (float*)(ws + 1968128);
    float* biasd1 = (float*)(ws + 1970688);
    float* biasd2 = (float*)(ws + 1972736);
    unsigned short* h    = (unsigned short*)(ws + 2097152);   // [B][512] bf16
    unsigned short* pib  = (unsigned short*)(ws + 35651584);  // [B][64]  bf16
    unsigned short* hdb  = h;                                  // reuse h
    // peak ws = 39.85 MB

    // ---- prep weights ----
    prep_bt<<<dim3(512 * 832 / 256), 256, 0, stream>>>(
        enc_w1, enc_b1, w1b, bias1, 784, 500, 832, 512);
    prep_wab<<<dim3(256), 256, 0, stream>>>(w_alpha, w_beta, b_alpha, b_beta, wab, biasab);
    prep_bt<<<dim3(512 * 64 / 256), 256, 0, stream>>>(
        dec_w1, dec_b1, dw1b, biasd1, 50, 500, 64, 512);
    prep_bt<<<dim3(896 * 512 / 256), 256, 0, stream>>>(
        dec_w2, dec_b2, dw2b, biasd2, 500, 784, 512, 896);

    // ---- GEMM1: h = relu(x @ enc_w1 + b1), f32-A gll staging + frag cvt ----
    mfma_gemm<0, true><<<dim3((512 / BN) * (BATCH / BM)), NTHR, 0, stream>>>(
        x, w1b, bias1, h, 832, 784, 784, 512, 500, 512 / BN);

    // ---- GEMM2/3: [alpha|beta] = softplus(h @ wab + b) ----
    mfma_gemm<1, false><<<dim3(BATCH / BM), NTHR, 0, stream>>>(
        h, wab, biasab, alpha, 512, 512, 512, 0, 100, 1);

    // ---- sample: one wave per row ----
    sample_pi<<<dim3(BATCH * 64 / 256), 256, 0, stream>>>(
        u, alpha, alpha + (size_t)BATCH * 50, pib);

    // ---- GEMM4: hd = relu(pib @ dec_w1 + b) ----
    mfma_gemm<0, false><<<dim3((512 / BN) * (BATCH / BM)), NTHR, 0, stream>>>(
        pib, dw1b, biasd1, hdb, 64, 64, 64, 512, 500, 512 / BN);

    // ---- GEMM5: recon = sigmoid(hd @ dec_w2 + b) ----
    mfma_gemm<2, false><<<dim3((896 / BN) * (BATCH / BM)), NTHR, 0, stream>>>(
        hdb, dw2b, biasd2, recon, 512, 512, 512, 784, 784, 896 / BN);
}

// Round 13
// 153.055 us; speedup vs baseline: 1.7034x; 1.0329x over previous
//
#include <hip/hip_runtime.h>
#include <math.h>

// StickBreakingVAE forward, all-bf16 MFMA pipeline, 8-wave blocks, XCD swizzle.
// r13: consolidation — separate cast_x (pure-BW f32->bf16) + ALL GEMMs in the
// proven bf16 single-buffered gll structure (GEMM5 measured ~860 TF in r8).
// Six fused-f32-A variants (r6-r12) all plateaued at 75-91 us vs 35 us for the
// same-FLOPs bf16 GEMM — fused cast abandoned on evidence.
// B=32768, D=784, H=500, K=50.
// cast_x: x f32 [B,784] -> xb bf16 [B,832]  (xb in d_out recon region, dead til GEMM5)
// GEMM1: h   = relu(xb @ enc_w1 + b)     K=832 N=512  (bf16, ws)
// GEMM2/3:   [alpha|beta] = softplus(h @ wab + b)  K=512 N=128 (f32 -> d_out)
// sample_pi: wave-per-row stick-breaking scan -> pib bf16 [B,64] (ws)
// GEMM4: hd  = relu(pib @ dec_w1 + b)    K=64  N=512  (bf16, reuses h region)
// GEMM5: rec = sigmoid(hd @ dec_w2 + b)  K=512 N=896  (f32 masked, overwrites xb)

typedef __bf16 bf16x8 __attribute__((ext_vector_type(8)));
typedef float f32x4 __attribute__((ext_vector_type(4)));

#define BATCH 32768
#define BM 128
#define BN 128
#define BK 64
#define NTHR 512

__device__ __forceinline__ unsigned short bf16_bits(float f) {
    __bf16 b = (__bf16)f;
    return __builtin_bit_cast(unsigned short, b);
}

__device__ __forceinline__ void gll16(const void* src, void* ldsdst) {
    __builtin_amdgcn_global_load_lds(
        (const __attribute__((address_space(1))) unsigned int*)src,
        (__attribute__((address_space(3))) unsigned int*)ldsdst,
        16, 0, 0);
}

// MODE 0: relu -> bf16 C [ldc]; MODE 1: softplus -> alpha/beta f32 compact;
// MODE 2: sigmoid -> f32 C [B,Nreal] masked.
template<int MODE>
__global__ __launch_bounds__(NTHR, 4) void mfma_gemm(
    const unsigned short* __restrict__ A,   // [M][lda] bf16 (zero-padded)
    const unsigned short* __restrict__ Bt,  // [Npad][Kpad] bf16 (zero-padded)
    const float* __restrict__ bias,         // [Npad]
    void* __restrict__ Cv,
    int Kpad, int lda, int ldc, int Nreal, int nbx)
{
    __shared__ unsigned short As[BM * BK];   // linear row*64 + swizzled-granule*8
    __shared__ unsigned short Bs[BN * BK];

    // ---- chunked bijective XCD swizzle (T1, m204) ----
    const int nwg = gridDim.x;
    const int orig = blockIdx.x;
    const int q = nwg >> 3, r8 = nwg & 7;
    const int xcd = orig & 7;
    const int chunkbase = (xcd < r8) ? xcd * (q + 1) : r8 * (q + 1) + (xcd - r8) * q;
    const int wgid = chunkbase + (orig >> 3);
    const int bn = wgid % nbx;               // n fastest -> A-panel L2 reuse
    const size_t block_m = (size_t)(wgid / nbx) * BM;
    const int block_n = bn * BN;

    const int tid = threadIdx.x;
    const int l = tid & 63;
    const int wid = tid >> 6;                // 0..7
    const int wr = wid >> 2, wc = wid & 3;   // wave tile: 64 rows x 32 cols

    const int lr = l & 15;
    const int kh = l >> 4;

    f32x4 acc[4][2] = {};

    for (int k0 = 0; k0 < Kpad; k0 += BK) {
        // stage B then A: linear LDS dest, XOR-pre-swizzled global source
        #pragma unroll
        for (int i = 0; i < 2; ++i) {
            int chunk = wid * 2 + i;          // 16 chunks x 64 granules(16B)
            int gid = chunk * 64 + l;         // granule 0..1023
            int r = gid >> 3;                 // tile row 0..127
            int kgs = (gid & 7) ^ (r & 7);    // swizzled source granule
            gll16(Bt + (size_t)(block_n + r) * Kpad + k0 + kgs * 8, Bs + chunk * 512);
        }
        #pragma unroll
        for (int i = 0; i < 2; ++i) {
            int chunk = wid * 2 + i;
            int gid = chunk * 64 + l;
            int r = gid >> 3;
            int kgs = (gid & 7) ^ (r & 7);
            gll16(A + (block_m + r) * (size_t)lda + k0 + kgs * 8, As + chunk * 512);
        }
        __syncthreads();

        #pragma unroll
        for (int s = 0; s < 2; ++s) {
            bf16x8 af[4], bf[2];
            #pragma unroll
            for (int mi = 0; mi < 4; ++mi) {
                int row = wr * 64 + mi * 16 + lr;
                int g = (s * 4 + kh) ^ (row & 7);
                af[mi] = *(const bf16x8*)(As + row * 64 + g * 8);
            }
            #pragma unroll
            for (int ni = 0; ni < 2; ++ni) {
                int row = wc * 32 + ni * 16 + lr;
                int g = (s * 4 + kh) ^ (row & 7);
                bf[ni] = *(const bf16x8*)(Bs + row * 64 + g * 8);
            }
            #pragma unroll
            for (int mi = 0; mi < 4; ++mi)
                #pragma unroll
                for (int ni = 0; ni < 2; ++ni)
                    acc[mi][ni] = __builtin_amdgcn_mfma_f32_16x16x32_bf16(
                        af[mi], bf[ni], acc[mi][ni], 0, 0, 0);
        }
        __syncthreads();
    }

    // epilogue: C/D layout col=lane&15, row=(lane>>4)*4+j
    const int rg = (l >> 4) * 4;
    #pragma unroll
    for (int mi = 0; mi < 4; ++mi) {
        #pragma unroll
        for (int ni = 0; ni < 2; ++ni) {
            int gn = block_n + wc * 32 + ni * 16 + lr;
            float bs = bias[gn];
            #pragma unroll
            for (int j = 0; j < 4; ++j) {
                long gm = block_m + wr * 64 + mi * 16 + rg + j;
                float z = acc[mi][ni][j] + bs;
                if (MODE == 0) {
                    z = fmaxf(z, 0.f);
                    ((unsigned short*)Cv)[gm * ldc + gn] = bf16_bits(z);
                } else if (MODE == 1) {
                    z = (z > 0.f) ? z + __logf(1.f + __expf(-z))
                                  : __logf(1.f + __expf(z));
                    float* out = (float*)Cv;
                    if (gn < 50)       out[gm * 50 + gn] = z;
                    else if (gn < 100) out[(size_t)BATCH * 50 + gm * 50 + (gn - 50)] = z;
                } else {
                    if (gn < Nreal) {
                        z = __fdividef(1.f, 1.f + __expf(-z));   // single-sided sigmoid
                        ((float*)Cv)[gm * Nreal + gn] = z;
                    }
                }
            }
        }
    }
}

// x f32 [B][784] -> xb bf16 [B][832] zero-padded (pure BW pass)
__global__ __launch_bounds__(256) void cast_x(
    const float* __restrict__ x, unsigned short* __restrict__ xb)
{
    int gid = blockIdx.x * 256 + threadIdx.x;   // granule of 8 elems; B*104 total
    int r = gid / 104;
    int c = gid - r * 104;
    union { __bf16 b[8]; uint4 u; } pk;
    if (c < 98) {
        const float4* p = (const float4*)(x + (size_t)r * 784 + c * 8);
        float4 f0 = p[0], f1 = p[1];
        pk.b[0] = (__bf16)f0.x; pk.b[1] = (__bf16)f0.y;
        pk.b[2] = (__bf16)f0.z; pk.b[3] = (__bf16)f0.w;
        pk.b[4] = (__bf16)f1.x; pk.b[5] = (__bf16)f1.y;
        pk.b[6] = (__bf16)f1.z; pk.b[7] = (__bf16)f1.w;
    } else {
        pk.u = make_uint4(0, 0, 0, 0);
    }
    *(uint4*)(xb + (size_t)r * 832 + c * 8) = pk.u;
}

// weight [Kr][Nr] f32 -> [Npad][Kpad] bf16 transposed, bias padded
__global__ __launch_bounds__(256) void prep_bt(
    const float* __restrict__ W, const float* __restrict__ bias,
    unsigned short* __restrict__ Bt, float* __restrict__ bpad,
    int Kr, int Nr, int Kpad, int Npad)
{
    int idx = blockIdx.x * 256 + threadIdx.x;
    if (idx >= Npad * Kpad) return;
    int n = idx / Kpad, k = idx - n * Kpad;
    float v = (n < Nr && k < Kr) ? W[(size_t)k * Nr + n] : 0.f;
    Bt[idx] = bf16_bits(v);
    if (k == 0) bpad[n] = (n < Nr) ? bias[n] : 0.f;
}

// [w_alpha | w_beta] -> [128][512] bf16 transposed
__global__ __launch_bounds__(256) void prep_wab(
    const float* __restrict__ Wa, const float* __restrict__ Wb,
    const float* __restrict__ ba, const float* __restrict__ bb,
    unsigned short* __restrict__ Bt, float* __restrict__ bpad)
{
    int idx = blockIdx.x * 256 + threadIdx.x;
    if (idx >= 128 * 512) return;
    int n = idx >> 9, k = idx & 511;
    float v = 0.f;
    if (k < 500) {
        if (n < 50)       v = Wa[(size_t)k * 50 + n];
        else if (n < 100) v = Wb[(size_t)k * 50 + (n - 50)];
    }
    Bt[idx] = bf16_bits(v);
    if (k == 0) bpad[n] = (n < 50) ? ba[n] : ((n < 100) ? bb[n - 50] : 0.f);
}

// Kumaraswamy sample + stick-breaking: one wave per row, shuffle prefix-product.
__global__ __launch_bounds__(256) void sample_pi(
    const float* __restrict__ u, const float* __restrict__ alpha,
    const float* __restrict__ beta, unsigned short* __restrict__ pib)
{
    int row = (blockIdx.x * 256 + threadIdx.x) >> 6;
    int lane = threadIdx.x & 63;
    size_t base = (size_t)row * 50;

    float v = 0.f, w = 1.f;
    if (lane < 50) {
        float a = alpha[base + lane];
        float b = beta[base + lane];
        float uu = u[base + lane];
        float t = exp2f(__fdividef(log2f(uu), b));          // u^(1/beta)
        v = exp2f(__fdividef(log2f(1.f - t), a));           // (1-t)^(1/alpha)
        w = 1.f - v;
    }
    float p = w;
    #pragma unroll
    for (int off = 1; off < 64; off <<= 1) {
        float t = __shfl_up(p, off, 64);
        if (lane >= off) p *= t;
    }
    float ex = __shfl_up(p, 1, 64);
    if (lane == 0) ex = 1.f;
    float pi = v * ex;
    pib[(size_t)row * 64 + lane] = (lane < 50) ? bf16_bits(pi) : (unsigned short)0;
}

extern "C" void kernel_launch(void* const* d_in, const int* in_sizes, int n_in,
                              void* d_out, int out_size, void* d_ws, size_t ws_size,
                              hipStream_t stream) {
    const float* x       = (const float*)d_in[0];
    const float* u       = (const float*)d_in[1];
    const float* enc_w1  = (const float*)d_in[2];
    const float* enc_b1  = (const float*)d_in[3];
    const float* w_alpha = (const float*)d_in[4];
    const float* b_alpha = (const float*)d_in[5];
    const float* w_beta  = (const float*)d_in[6];
    const float* b_beta  = (const float*)d_in[7];
    const float* dec_w1  = (const float*)d_in[8];
    const float* dec_b1  = (const float*)d_in[9];
    const float* dec_w2  = (const float*)d_in[10];
    const float* dec_b2  = (const float*)d_in[11];

    const int D = 784;

    float* out   = (float*)d_out;
    float* recon = out;                              // [B,784] f32
    float* alpha = out + (size_t)BATCH * D;          // [B,50]; beta at +B*50

    // xb scratch in d_out recon region (54.5 MB < alpha offset 102.8 MB)
    unsigned short* xb = (unsigned short*)d_out;     // [B][832] bf16

    // workspace layout
    char* ws = (char*)d_ws;
    unsigned short* w1b  = (unsigned short*)(ws);             // 512*832*2
    unsigned short* wab  = (unsigned short*)(ws + 851968);    // 128*512*2
    unsigned short* dw1b = (unsigned short*)(ws + 983040);    // 512*64*2
    unsigned short* dw2b = (unsigned short*)(ws + 1048576);   // 896*512*2
    float* bias1  = (float*)(ws + 1966080);
    float* biasab = (float*)(ws + 1968128);
    float* biasd1 = (float*)(ws + 1970688);
    float* biasd2 = (float*)(ws + 1972736);
    unsigned short* h    = (unsigned short*)(ws + 2097152);   // [B][512] bf16
    unsigned short* pib  = (unsigned short*)(ws + 35651584);  // [B][64]  bf16
    unsigned short* hdb  = h;                                  // reuse h
    // peak ws = 39.85 MB

    // ---- cast first (longest prep), then weight preps ----
    cast_x<<<dim3(BATCH * 104 / 256), 256, 0, stream>>>(x, xb);
    prep_bt<<<dim3(512 * 832 / 256), 256, 0, stream>>>(
        enc_w1, enc_b1, w1b, bias1, 784, 500, 832, 512);
    prep_wab<<<dim3(256), 256, 0, stream>>>(w_alpha, w_beta, b_alpha, b_beta, wab, biasab);
    prep_bt<<<dim3(512 * 64 / 256), 256, 0, stream>>>(
        dec_w1, dec_b1, dw1b, biasd1, 50, 500, 64, 512);
    prep_bt<<<dim3(896 * 512 / 256), 256, 0, stream>>>(
        dec_w2, dec_b2, dw2b, biasd2, 500, 784, 512, 896);

    // ---- GEMM1: h = relu(xb @ enc_w1 + b1) ----
    mfma_gemm<0><<<dim3((512 / BN) * (BATCH / BM)), NTHR, 0, stream>>>(
        xb, w1b, bias1, h, 832, 832, 512, 500, 512 / BN);

    // ---- GEMM2/3: [alpha|beta] = softplus(h @ wab + b) ----
    mfma_gemm<1><<<dim3(BATCH / BM), NTHR, 0, stream>>>(
        h, wab, biasab, alpha, 512, 512, 0, 100, 1);

    // ---- sample: one wave per row ----
    sample_pi<<<dim3(BATCH * 64 / 256), 256, 0, stream>>>(
        u, alpha, alpha + (size_t)BATCH * 50, pib);

    // ---- GEMM4: hd = relu(pib @ dec_w1 + b) ----
    mfma_gemm<0><<<dim3((512 / BN) * (BATCH / BM)), NTHR, 0, stream>>>(
        pib, dw1b, biasd1, hdb, 64, 64, 512, 500, 512 / BN);

    // ---- GEMM5: recon = sigmoid(hd @ dec_w2 + b) (overwrites xb) ----
    mfma_gemm<2><<<dim3((896 / BN) * (BATCH / BM)), NTHR, 0, stream>>>(
        hdb, dw2b, biasd2, recon, 512, 512, 784, 784, 896 / BN);
}

// Round 14
// 150.760 us; speedup vs baseline: 1.7294x; 1.0152x over previous
//
#include <hip/hip_runtime.h>
#include <math.h>

// StickBreakingVAE forward, all-bf16 MFMA pipeline, 8-wave blocks, XCD swizzle.
// r14: launch/overhead consolidation on top of r13's proven structure:
//  - sample_pi + GEMM4 fused (pi computed in-block -> swizzled LDS, no global pib;
//    dec_w1 staged per 128-col tile, double-buffered; 4-step n-loop)
//  - 4 weight-prep kernels merged into prep_all (blockIdx-range dispatch)
// Kernels: cast_x, prep_all, GEMM1, GEMM2/3, sample_gemm4, GEMM5.
// B=32768, D=784, H=500, K=50.

typedef __bf16 bf16x8 __attribute__((ext_vector_type(8)));
typedef float f32x4 __attribute__((ext_vector_type(4)));

#define BATCH 32768
#define BM 128
#define BN 128
#define BK 64
#define NTHR 512

__device__ __forceinline__ unsigned short bf16_bits(float f) {
    __bf16 b = (__bf16)f;
    return __builtin_bit_cast(unsigned short, b);
}

__device__ __forceinline__ void gll16(const void* src, void* ldsdst) {
    __builtin_amdgcn_global_load_lds(
        (const __attribute__((address_space(1))) unsigned int*)src,
        (__attribute__((address_space(3))) unsigned int*)ldsdst,
        16, 0, 0);
}

// MODE 0: relu -> bf16 C [ldc]; MODE 1: softplus -> alpha/beta f32 compact;
// MODE 2: sigmoid -> f32 C [B,Nreal] masked.
template<int MODE>
__global__ __launch_bounds__(NTHR, 4) void mfma_gemm(
    const unsigned short* __restrict__ A,   // [M][lda] bf16 (zero-padded)
    const unsigned short* __restrict__ Bt,  // [Npad][Kpad] bf16 (zero-padded)
    const float* __restrict__ bias,         // [Npad]
    void* __restrict__ Cv,
    int Kpad, int lda, int ldc, int Nreal, int nbx)
{
    __shared__ unsigned short As[BM * BK];   // linear row*64 + swizzled-granule*8
    __shared__ unsigned short Bs[BN * BK];

    // ---- chunked bijective XCD swizzle (T1, m204) ----
    const int nwg = gridDim.x;
    const int orig = blockIdx.x;
    const int q = nwg >> 3, r8 = nwg & 7;
    const int xcd = orig & 7;
    const int chunkbase = (xcd < r8) ? xcd * (q + 1) : r8 * (q + 1) + (xcd - r8) * q;
    const int wgid = chunkbase + (orig >> 3);
    const int bn = wgid % nbx;               // n fastest -> A-panel L2 reuse
    const size_t block_m = (size_t)(wgid / nbx) * BM;
    const int block_n = bn * BN;

    const int tid = threadIdx.x;
    const int l = tid & 63;
    const int wid = tid >> 6;                // 0..7
    const int wr = wid >> 2, wc = wid & 3;   // wave tile: 64 rows x 32 cols

    const int lr = l & 15;
    const int kh = l >> 4;

    f32x4 acc[4][2] = {};

    for (int k0 = 0; k0 < Kpad; k0 += BK) {
        // stage B then A: linear LDS dest, XOR-pre-swizzled global source
        #pragma unroll
        for (int i = 0; i < 2; ++i) {
            int chunk = wid * 2 + i;          // 16 chunks x 64 granules(16B)
            int gid = chunk * 64 + l;         // granule 0..1023
            int r = gid >> 3;                 // tile row 0..127
            int kgs = (gid & 7) ^ (r & 7);    // swizzled source granule
            gll16(Bt + (size_t)(block_n + r) * Kpad + k0 + kgs * 8, Bs + chunk * 512);
        }
        #pragma unroll
        for (int i = 0; i < 2; ++i) {
            int chunk = wid * 2 + i;
            int gid = chunk * 64 + l;
            int r = gid >> 3;
            int kgs = (gid & 7) ^ (r & 7);
            gll16(A + (block_m + r) * (size_t)lda + k0 + kgs * 8, As + chunk * 512);
        }
        __syncthreads();

        #pragma unroll
        for (int s = 0; s < 2; ++s) {
            bf16x8 af[4], bf[2];
            #pragma unroll
            for (int mi = 0; mi < 4; ++mi) {
                int row = wr * 64 + mi * 16 + lr;
                int g = (s * 4 + kh) ^ (row & 7);
                af[mi] = *(const bf16x8*)(As + row * 64 + g * 8);
            }
            #pragma unroll
            for (int ni = 0; ni < 2; ++ni) {
                int row = wc * 32 + ni * 16 + lr;
                int g = (s * 4 + kh) ^ (row & 7);
                bf[ni] = *(const bf16x8*)(Bs + row * 64 + g * 8);
            }
            #pragma unroll
            for (int mi = 0; mi < 4; ++mi)
                #pragma unroll
                for (int ni = 0; ni < 2; ++ni)
                    acc[mi][ni] = __builtin_amdgcn_mfma_f32_16x16x32_bf16(
                        af[mi], bf[ni], acc[mi][ni], 0, 0, 0);
        }
        __syncthreads();
    }

    // epilogue: C/D layout col=lane&15, row=(lane>>4)*4+j
    const int rg = (l >> 4) * 4;
    #pragma unroll
    for (int mi = 0; mi < 4; ++mi) {
        #pragma unroll
        for (int ni = 0; ni < 2; ++ni) {
            int gn = block_n + wc * 32 + ni * 16 + lr;
            float bs = bias[gn];
            #pragma unroll
            for (int j = 0; j < 4; ++j) {
                long gm = block_m + wr * 64 + mi * 16 + rg + j;
                float z = acc[mi][ni][j] + bs;
                if (MODE == 0) {
                    z = fmaxf(z, 0.f);
                    ((unsigned short*)Cv)[gm * ldc + gn] = bf16_bits(z);
                } else if (MODE == 1) {
                    z = (z > 0.f) ? z + __logf(1.f + __expf(-z))
                                  : __logf(1.f + __expf(z));
                    float* out = (float*)Cv;
                    if (gn < 50)       out[gm * 50 + gn] = z;
                    else if (gn < 100) out[(size_t)BATCH * 50 + gm * 50 + (gn - 50)] = z;
                } else {
                    if (gn < Nreal) {
                        z = __fdividef(1.f, 1.f + __expf(-z));   // single-sided sigmoid
                        ((float*)Cv)[gm * Nreal + gn] = z;
                    }
                }
            }
        }
    }
}

// Fused sample_pi + GEMM4: hd = relu(pi @ dec_w1 + b), pi never leaves the block.
// Block = 128 rows; 8 waves x 16 rows sample phase -> swizzled Pi LDS;
// n-loop over 4 x 128-col tiles of dw1b (double-buffered, staged via gll).
__global__ __launch_bounds__(NTHR, 4) void sample_gemm4(
    const float* __restrict__ u, const float* __restrict__ alpha,
    const float* __restrict__ beta,
    const unsigned short* __restrict__ dw1b,   // [512][64] bf16 zero-padded
    const float* __restrict__ biasd1,          // [512]
    unsigned short* __restrict__ hdb)          // [B][512] bf16
{
    __shared__ unsigned short Pi[128 * 64];        // 16KB, swizzled granules
    __shared__ unsigned short Wd[2][128 * 64];     // 2 x 16KB dbuf

    const int tid = threadIdx.x;
    const int l = tid & 63;
    const int wid = tid >> 6;

    // XCD swizzle (nbx=1): chunked bijective m-block mapping
    const int nwg = gridDim.x;                     // 256
    const int orig = blockIdx.x;
    const int q = nwg >> 3, r8 = nwg & 7;
    const int xcd = orig & 7;
    const int chunkbase = (xcd < r8) ? xcd * (q + 1) : r8 * (q + 1) + (xcd - r8) * q;
    const int wgid = chunkbase + (orig >> 3);
    const size_t block_m = (size_t)wgid * 128;

    auto stageW = [&](int j, int buf) {            // 128 rows of dw1b tile j
        #pragma unroll
        for (int i = 0; i < 2; ++i) {
            int chunk = wid * 2 + i;
            int gid = chunk * 64 + l;              // granule 0..1023
            int r = gid >> 3;                      // row-in-tile 0..127
            int kgs = (gid & 7) ^ (r & 7);
            gll16(dw1b + (size_t)(j * 128 + r) * 64 + kgs * 8,
                  &Wd[buf][chunk * 512]);
        }
    };

    stageW(0, 0);

    // ---- sample phase: wave wid handles rows wid*16 .. +15 ----
    for (int rr = 0; rr < 16; ++rr) {
        int row = wid * 16 + rr;
        size_t grow = block_m + row;
        float v = 0.f, w = 1.f;
        if (l < 50) {
            float a = alpha[grow * 50 + l];
            float b = beta[grow * 50 + l];
            float uu = u[grow * 50 + l];
            float t = exp2f(__fdividef(log2f(uu), b));       // u^(1/beta)
            v = exp2f(__fdividef(log2f(1.f - t), a));        // (1-t)^(1/alpha)
            w = 1.f - v;
        }
        float p = w;
        #pragma unroll
        for (int off = 1; off < 64; off <<= 1) {
            float t2 = __shfl_up(p, off, 64);
            if (l >= off) p *= t2;
        }
        float ex = __shfl_up(p, 1, 64);
        if (l == 0) ex = 1.f;
        float pi = (l < 50) ? v * ex : 0.f;
        // swizzled element store: elem l of row -> granule slot (l>>3)^(row&7)
        Pi[row * 64 + (((l >> 3) ^ (row & 7)) << 3) + (l & 7)] = bf16_bits(pi);
    }
    __syncthreads();   // Pi + Wd[0] ready

    const int lr = l & 15, kh = l >> 4;
    const int wr = wid >> 2, wc = wid & 3;   // wave tile: 64 rows x 32 cols
    const int rg = (l >> 4) * 4;

    for (int j = 0; j < 4; ++j) {            // 4 n-tiles of 128
        if (j < 3) stageW(j + 1, (j + 1) & 1);
        f32x4 acc[4][2] = {};
        const unsigned short* W = Wd[j & 1];
        #pragma unroll
        for (int s = 0; s < 2; ++s) {
            bf16x8 af[4], bf[2];
            #pragma unroll
            for (int mi = 0; mi < 4; ++mi) {
                int row = wr * 64 + mi * 16 + lr;
                int g = (s * 4 + kh) ^ (row & 7);
                af[mi] = *(const bf16x8*)(Pi + row * 64 + g * 8);
            }
            #pragma unroll
            for (int ni = 0; ni < 2; ++ni) {
                int row = wc * 32 + ni * 16 + lr;
                int g = (s * 4 + kh) ^ (row & 7);
                bf[ni] = *(const bf16x8*)(W + row * 64 + g * 8);
            }
            #pragma unroll
            for (int mi = 0; mi < 4; ++mi)
                #pragma unroll
                for (int ni = 0; ni < 2; ++ni)
                    acc[mi][ni] = __builtin_amdgcn_mfma_f32_16x16x32_bf16(
                        af[mi], bf[ni], acc[mi][ni], 0, 0, 0);
        }
        // epilogue tile j: relu -> hdb
        #pragma unroll
        for (int mi = 0; mi < 4; ++mi) {
            #pragma unroll
            for (int ni = 0; ni < 2; ++ni) {
                int gn = j * 128 + wc * 32 + ni * 16 + lr;
                float bs = biasd1[gn];
                #pragma unroll
                for (int jj = 0; jj < 4; ++jj) {
                    long gm = block_m + wr * 64 + mi * 16 + rg + jj;
                    float z = fmaxf(acc[mi][ni][jj] + bs, 0.f);
                    hdb[gm * 512 + gn] = bf16_bits(z);
                }
            }
        }
        __syncthreads();   // all reads of Wd[j&1] done + Wd[(j+1)&1] landed
    }
}

// x f32 [B][784] -> xb bf16 [B][832] zero-padded (pure BW pass)
__global__ __launch_bounds__(256) void cast_x(
    const float* __restrict__ x, unsigned short* __restrict__ xb)
{
    int gid = blockIdx.x * 256 + threadIdx.x;   // granule of 8 elems; B*104 total
    int r = gid / 104;
    int c = gid - r * 104;
    union { __bf16 b[8]; uint4 u; } pk;
    if (c < 98) {
        const float4* p = (const float4*)(x + (size_t)r * 784 + c * 8);
        float4 f0 = p[0], f1 = p[1];
        pk.b[0] = (__bf16)f0.x; pk.b[1] = (__bf16)f0.y;
        pk.b[2] = (__bf16)f0.z; pk.b[3] = (__bf16)f0.w;
        pk.b[4] = (__bf16)f1.x; pk.b[5] = (__bf16)f1.y;
        pk.b[6] = (__bf16)f1.z; pk.b[7] = (__bf16)f1.w;
    } else {
        pk.u = make_uint4(0, 0, 0, 0);
    }
    *(uint4*)(xb + (size_t)r * 832 + c * 8) = pk.u;
}

// All weight preps in one kernel (blockIdx-range dispatch):
//  [0,1664):    enc_w1 [784][500] -> w1b [512][832] + bias1
//  [1664,1920): [w_alpha|w_beta]  -> wab [128][512] + biasab
//  [1920,2048): dec_w1 [50][500]  -> dw1b [512][64] + biasd1
//  [2048,3840): dec_w2 [500][784] -> dw2b [896][512] + biasd2
__global__ __launch_bounds__(256) void prep_all(
    const float* __restrict__ enc_w1, const float* __restrict__ enc_b1,
    const float* __restrict__ Wa, const float* __restrict__ ba,
    const float* __restrict__ Wb, const float* __restrict__ bb,
    const float* __restrict__ dec_w1, const float* __restrict__ dec_b1,
    const float* __restrict__ dec_w2, const float* __restrict__ dec_b2,
    unsigned short* __restrict__ w1b, float* __restrict__ bias1,
    unsigned short* __restrict__ wab, float* __restrict__ biasab,
    unsigned short* __restrict__ dw1b, float* __restrict__ biasd1,
    unsigned short* __restrict__ dw2b, float* __restrict__ biasd2)
{
    int bid = blockIdx.x;
    int t = threadIdx.x;
    if (bid < 1664) {                    // w1b: Kr=784 Nr=500 Kpad=832 Npad=512
        int idx = bid * 256 + t;
        int n = idx / 832, k = idx - n * 832;
        float v = (n < 500 && k < 784) ? enc_w1[(size_t)k * 500 + n] : 0.f;
        w1b[idx] = bf16_bits(v);
        if (k == 0) bias1[n] = (n < 500) ? enc_b1[n] : 0.f;
    } else if (bid < 1920) {             // wab: [128][512]
        int idx = (bid - 1664) * 256 + t;
        int n = idx >> 9, k = idx & 511;
        float v = 0.f;
        if (k < 500) {
            if (n < 50)       v = Wa[(size_t)k * 50 + n];
            else if (n < 100) v = Wb[(size_t)k * 50 + (n - 50)];
        }
        wab[idx] = bf16_bits(v);
        if (k == 0) biasab[n] = (n < 50) ? ba[n] : ((n < 100) ? bb[n - 50] : 0.f);
    } else if (bid < 2048) {             // dw1b: Kr=50 Nr=500 Kpad=64 Npad=512
        int idx = (bid - 1920) * 256 + t;
        int n = idx >> 6, k = idx & 63;
        float v = (n < 500 && k < 50) ? dec_w1[(size_t)k * 500 + n] : 0.f;
        dw1b[idx] = bf16_bits(v);
        if (k == 0) biasd1[n] = (n < 500) ? dec_b1[n] : 0.f;
    } else {                             // dw2b: Kr=500 Nr=784 Kpad=512 Npad=896
        int idx = (bid - 2048) * 256 + t;
        int n = idx >> 9, k = idx & 511;
        float v = (n < 784 && k < 500) ? dec_w2[(size_t)k * 784 + n] : 0.f;
        dw2b[idx] = bf16_bits(v);
        if (k == 0) biasd2[n] = (n < 784) ? dec_b2[n] : 0.f;
    }
}

extern "C" void kernel_launch(void* const* d_in, const int* in_sizes, int n_in,
                              void* d_out, int out_size, void* d_ws, size_t ws_size,
                              hipStream_t stream) {
    const float* x       = (const float*)d_in[0];
    const float* u       = (const float*)d_in[1];
    const float* enc_w1  = (const float*)d_in[2];
    const float* enc_b1  = (const float*)d_in[3];
    const float* w_alpha = (const float*)d_in[4];
    const float* b_alpha = (const float*)d_in[5];
    const float* w_beta  = (const float*)d_in[6];
    const float* b_beta  = (const float*)d_in[7];
    const float* dec_w1  = (const float*)d_in[8];
    const float* dec_b1  = (const float*)d_in[9];
    const float* dec_w2  = (const float*)d_in[10];
    const float* dec_b2  = (const float*)d_in[11];

    const int D = 784;

    float* out   = (float*)d_out;
    float* recon = out;                              // [B,784] f32
    float* alpha = out + (size_t)BATCH * D;          // [B,50]; beta at +B*50

    // xb scratch in d_out recon region (54.5 MB < alpha offset 102.8 MB)
    unsigned short* xb = (unsigned short*)d_out;     // [B][832] bf16

    // workspace layout
    char* ws = (char*)d_ws;
    unsigned short* w1b  = (unsigned short*)(ws);             // 512*832*2
    unsigned short* wab  = (unsigned short*)(ws + 851968);    // 128*512*2
    unsigned short* dw1b = (unsigned short*)(ws + 983040);    // 512*64*2
    unsigned short* dw2b = (unsigned short*)(ws + 1048576);   // 896*512*2
    float* bias1  = (float*)(ws + 1966080);
    float* biasab = (float*)(ws + 1968128);
    float* biasd1 = (float*)(ws + 1970688);
    float* biasd2 = (float*)(ws + 1972736);
    unsigned short* h    = (unsigned short*)(ws + 2097152);   // [B][512] bf16
    unsigned short* hdb  = h;                                  // reuse h
    // peak ws = 35.7 MB

    // ---- cast + merged preps ----
    cast_x<<<dim3(BATCH * 104 / 256), 256, 0, stream>>>(x, xb);
    prep_all<<<dim3(3840), 256, 0, stream>>>(
        enc_w1, enc_b1, w_alpha, b_alpha, w_beta, b_beta,
        dec_w1, dec_b1, dec_w2, dec_b2,
        w1b, bias1, wab, biasab, dw1b, biasd1, dw2b, biasd2);

    // ---- GEMM1: h = relu(xb @ enc_w1 + b1) ----
    mfma_gemm<0><<<dim3((512 / BN) * (BATCH / BM)), NTHR, 0, stream>>>(
        xb, w1b, bias1, h, 832, 832, 512, 500, 512 / BN);

    // ---- GEMM2/3: [alpha|beta] = softplus(h @ wab + b) ----
    mfma_gemm<1><<<dim3(BATCH / BM), NTHR, 0, stream>>>(
        h, wab, biasab, alpha, 512, 512, 0, 100, 1);

    // ---- fused sample + GEMM4: hd = relu(pi @ dec_w1 + b) ----
    sample_gemm4<<<dim3(BATCH / 128), NTHR, 0, stream>>>(
        u, alpha, alpha + (size_t)BATCH * 50, dw1b, biasd1, hdb);

    // ---- GEMM5: recon = sigmoid(hd @ dec_w2 + b) (overwrites xb) ----
    mfma_gemm<2><<<dim3((896 / BN) * (BATCH / BM)), NTHR, 0, stream>>>(
        hdb, dw2b, biasd2, recon, 512, 512, 784, 784, 896 / BN);
}

// Round 15
// 145.057 us; speedup vs baseline: 1.7973x; 1.0393x over previous
//
#include <hip/hip_runtime.h>
#include <math.h>

// StickBreakingVAE forward, all-bf16 MFMA, 8-wave blocks, XCD swizzle.
// r15: mid-pipeline mega-fusion. Kernels: prep_cast, GEMM1, mid_fused, GEMM5.
//  mid_fused (grid 256, 112KB LDS): per 128-row block
//    P1: [alpha|beta] pre-act = h @ wab (K=512, 2-barrier gll loop)
//    P2: softplus -> d_out alpha/beta AND LDS ab[2][128][64] f32
//    P3: sample (a,b from LDS, u reg-hoisted) -> Pi LDS (swizzled)
//    P4: hd = relu(pi @ dec_w1 + b) (dbuf'd 4-tile n-loop, r14-proven)
//  hdb aliases h (each block consumes its h rows in P1 before P4 overwrite).
// B=32768, D=784, H=500, K=50.

typedef __bf16 bf16x8 __attribute__((ext_vector_type(8)));
typedef float f32x4 __attribute__((ext_vector_type(4)));

#define BATCH 32768
#define BM 128
#define BN 128
#define BK 64
#define NTHR 512

__device__ __forceinline__ unsigned short bf16_bits(float f) {
    __bf16 b = (__bf16)f;
    return __builtin_bit_cast(unsigned short, b);
}

__device__ __forceinline__ void gll16(const void* src, void* ldsdst) {
    __builtin_amdgcn_global_load_lds(
        (const __attribute__((address_space(1))) unsigned int*)src,
        (__attribute__((address_space(3))) unsigned int*)ldsdst,
        16, 0, 0);
}

// chunked bijective XCD swizzle (T1, m204)
__device__ __forceinline__ int xcd_swz(int orig, int nwg) {
    int q = nwg >> 3, r8 = nwg & 7;
    int xcd = orig & 7;
    int chunkbase = (xcd < r8) ? xcd * (q + 1) : r8 * (q + 1) + (xcd - r8) * q;
    return chunkbase + (orig >> 3);
}

// MODE 0: relu -> bf16 C [ldc]; MODE 2: sigmoid -> f32 C [B,Nreal] masked.
template<int MODE>
__global__ __launch_bounds__(NTHR, 4) void mfma_gemm(
    const unsigned short* __restrict__ A,   // [M][lda] bf16 (zero-padded)
    const unsigned short* __restrict__ Bt,  // [Npad][Kpad] bf16 (zero-padded)
    const float* __restrict__ bias,         // [Npad]
    void* __restrict__ Cv,
    int Kpad, int lda, int ldc, int Nreal, int nbx)
{
    __shared__ unsigned short As[BM * BK];
    __shared__ unsigned short Bs[BN * BK];

    const int wgid = xcd_swz(blockIdx.x, gridDim.x);
    const int bn = wgid % nbx;
    const size_t block_m = (size_t)(wgid / nbx) * BM;
    const int block_n = bn * BN;

    const int tid = threadIdx.x;
    const int l = tid & 63;
    const int wid = tid >> 6;
    const int wr = wid >> 2, wc = wid & 3;   // wave tile 64x32
    const int lr = l & 15;
    const int kh = l >> 4;

    f32x4 acc[4][2] = {};

    for (int k0 = 0; k0 < Kpad; k0 += BK) {
        #pragma unroll
        for (int i = 0; i < 2; ++i) {
            int chunk = wid * 2 + i;
            int gid = chunk * 64 + l;
            int r = gid >> 3;
            int kgs = (gid & 7) ^ (r & 7);
            gll16(Bt + (size_t)(block_n + r) * Kpad + k0 + kgs * 8, Bs + chunk * 512);
        }
        #pragma unroll
        for (int i = 0; i < 2; ++i) {
            int chunk = wid * 2 + i;
            int gid = chunk * 64 + l;
            int r = gid >> 3;
            int kgs = (gid & 7) ^ (r & 7);
            gll16(A + (block_m + r) * (size_t)lda + k0 + kgs * 8, As + chunk * 512);
        }
        __syncthreads();
        #pragma unroll
        for (int s = 0; s < 2; ++s) {
            bf16x8 af[4], bf[2];
            #pragma unroll
            for (int mi = 0; mi < 4; ++mi) {
                int row = wr * 64 + mi * 16 + lr;
                int g = (s * 4 + kh) ^ (row & 7);
                af[mi] = *(const bf16x8*)(As + row * 64 + g * 8);
            }
            #pragma unroll
            for (int ni = 0; ni < 2; ++ni) {
                int row = wc * 32 + ni * 16 + lr;
                int g = (s * 4 + kh) ^ (row & 7);
                bf[ni] = *(const bf16x8*)(Bs + row * 64 + g * 8);
            }
            #pragma unroll
            for (int mi = 0; mi < 4; ++mi)
                #pragma unroll
                for (int ni = 0; ni < 2; ++ni)
                    acc[mi][ni] = __builtin_amdgcn_mfma_f32_16x16x32_bf16(
                        af[mi], bf[ni], acc[mi][ni], 0, 0, 0);
        }
        __syncthreads();
    }

    const int rg = (l >> 4) * 4;
    #pragma unroll
    for (int mi = 0; mi < 4; ++mi) {
        #pragma unroll
        for (int ni = 0; ni < 2; ++ni) {
            int gn = block_n + wc * 32 + ni * 16 + lr;
            float bs = bias[gn];
            #pragma unroll
            for (int j = 0; j < 4; ++j) {
                long gm = block_m + wr * 64 + mi * 16 + rg + j;
                float z = acc[mi][ni][j] + bs;
                if (MODE == 0) {
                    z = fmaxf(z, 0.f);
                    ((unsigned short*)Cv)[gm * ldc + gn] = bf16_bits(z);
                } else {
                    if (gn < Nreal) {
                        z = __fdividef(1.f, 1.f + __expf(-z));
                        ((float*)Cv)[gm * Nreal + gn] = z;
                    }
                }
            }
        }
    }
}

// Fused GEMM2/3 + softplus + sample + GEMM4. Grid 256 x 512thr, 112KB LDS.
__global__ __launch_bounds__(NTHR, 2) void mid_fused(
    const unsigned short* __restrict__ h,      // [B][512] bf16
    const unsigned short* __restrict__ wab,    // [128][512] bf16
    const float* __restrict__ biasab,          // [128]
    const float* __restrict__ u,               // [B][50] f32
    const unsigned short* __restrict__ dw1b,   // [512][64] bf16
    const float* __restrict__ biasd1,          // [512]
    float* __restrict__ outAB,                 // alpha base (d_out + B*784)
    unsigned short* __restrict__ hdb)          // [B][512] bf16 (aliases h)
{
    __shared__ __align__(16) unsigned char smem[114688];   // 112 KB
    float* ab = (float*)smem;                          // [2][128][64] f32, 64KB
    unsigned short* Pi = (unsigned short*)(smem + 65536);       // [128][64], 16KB
    unsigned short* Wd = (unsigned short*)(smem + 81920);       // [2][128][64], 32KB
    unsigned short* As = (unsigned short*)(smem + 81920);       // P1 alias
    unsigned short* Bs = (unsigned short*)(smem + 81920 + 16384);

    const int tid = threadIdx.x;
    const int l = tid & 63;
    const int wid = tid >> 6;
    const int wr = wid >> 2, wc = wid & 3;
    const int lr = l & 15;
    const int kh = l >> 4;
    const int rg = (l >> 4) * 4;

    const int wgid = xcd_swz(blockIdx.x, gridDim.x);
    const size_t block_m = (size_t)wgid * 128;

    // ---- P1: alpha/beta pre-act = h @ wab, K=512 ----
    {
        f32x4 acc[4][2] = {};
        for (int k0 = 0; k0 < 512; k0 += BK) {
            #pragma unroll
            for (int i = 0; i < 2; ++i) {
                int chunk = wid * 2 + i;
                int gid = chunk * 64 + l;
                int r = gid >> 3;
                int kgs = (gid & 7) ^ (r & 7);
                gll16(wab + (size_t)r * 512 + k0 + kgs * 8, Bs + chunk * 512);
            }
            #pragma unroll
            for (int i = 0; i < 2; ++i) {
                int chunk = wid * 2 + i;
                int gid = chunk * 64 + l;
                int r = gid >> 3;
                int kgs = (gid & 7) ^ (r & 7);
                gll16(h + (block_m + r) * 512 + k0 + kgs * 8, As + chunk * 512);
            }
            __syncthreads();
            #pragma unroll
            for (int s = 0; s < 2; ++s) {
                bf16x8 af[4], bf[2];
                #pragma unroll
                for (int mi = 0; mi < 4; ++mi) {
                    int row = wr * 64 + mi * 16 + lr;
                    int g = (s * 4 + kh) ^ (row & 7);
                    af[mi] = *(const bf16x8*)(As + row * 64 + g * 8);
                }
                #pragma unroll
                for (int ni = 0; ni < 2; ++ni) {
                    int row = wc * 32 + ni * 16 + lr;
                    int g = (s * 4 + kh) ^ (row & 7);
                    bf[ni] = *(const bf16x8*)(Bs + row * 64 + g * 8);
                }
                #pragma unroll
                for (int mi = 0; mi < 4; ++mi)
                    #pragma unroll
                    for (int ni = 0; ni < 2; ++ni)
                        acc[mi][ni] = __builtin_amdgcn_mfma_f32_16x16x32_bf16(
                            af[mi], bf[ni], acc[mi][ni], 0, 0, 0);
            }
            __syncthreads();   // last iter: As/Bs reads done -> Wd region reusable
        }

        // ---- stage dec_w1 tile 0 early (lands during P2/P3) ----
        #pragma unroll
        for (int i = 0; i < 2; ++i) {
            int chunk = wid * 2 + i;
            int gid = chunk * 64 + l;
            int r = gid >> 3;
            int kgs = (gid & 7) ^ (r & 7);
            gll16(dw1b + (size_t)r * 64 + kgs * 8, Wd + chunk * 512);
        }

        // ---- P2: softplus -> d_out + LDS ab ----
        #pragma unroll
        for (int mi = 0; mi < 4; ++mi) {
            #pragma unroll
            for (int ni = 0; ni < 2; ++ni) {
                int gn = wc * 32 + ni * 16 + lr;       // 0..127
                float bs = biasab[gn];
                #pragma unroll
                for (int j = 0; j < 4; ++j) {
                    int lm = wr * 64 + mi * 16 + rg + j;
                    long gm = block_m + lm;
                    float z = acc[mi][ni][j] + bs;
                    z = (z > 0.f) ? z + __logf(1.f + __expf(-z))
                                  : __logf(1.f + __expf(z));
                    if (gn < 50) {
                        outAB[gm * 50 + gn] = z;
                        ab[lm * 64 + gn] = z;                       // alpha
                    } else if (gn < 100) {
                        outAB[(size_t)BATCH * 50 + gm * 50 + (gn - 50)] = z;
                        ab[128 * 64 + lm * 64 + (gn - 50)] = z;     // beta
                    }
                }
            }
        }
    }

    // ---- P3: sample. u hoisted to regs BEFORE barrier; a,b from LDS ----
    float ur[16];
    #pragma unroll
    for (int rr = 0; rr < 16; ++rr) {
        size_t grow = block_m + wid * 16 + rr;
        ur[rr] = (l < 50) ? u[grow * 50 + l] : 0.5f;
    }
    __syncthreads();   // ab visible (drains vmcnt too; Wd tile0 landed)

    #pragma unroll
    for (int rr = 0; rr < 16; ++rr) {
        int row = wid * 16 + rr;
        float v = 0.f, w = 1.f;
        if (l < 50) {
            float a = ab[row * 64 + l];
            float b = ab[128 * 64 + row * 64 + l];
            float t = exp2f(__fdividef(log2f(ur[rr]), b));      // u^(1/beta)
            v = exp2f(__fdividef(log2f(1.f - t), a));           // (1-t)^(1/alpha)
            w = 1.f - v;
        }
        float p = w;
        #pragma unroll
        for (int off = 1; off < 64; off <<= 1) {
            float t2 = __shfl_up(p, off, 64);
            if (l >= off) p *= t2;
        }
        float ex = __shfl_up(p, 1, 64);
        if (l == 0) ex = 1.f;
        float pi = (l < 50) ? v * ex : 0.f;
        Pi[row * 64 + (((l >> 3) ^ (row & 7)) << 3) + (l & 7)] = bf16_bits(pi);
    }
    __syncthreads();   // Pi ready

    // ---- P4: hd = relu(pi @ dec_w1 + b), 4 n-tiles, Wd dbuf ----
    for (int j = 0; j < 4; ++j) {
        if (j < 3) {
            int buf = (j + 1) & 1;
            #pragma unroll
            for (int i = 0; i < 2; ++i) {
                int chunk = wid * 2 + i;
                int gid = chunk * 64 + l;
                int r = gid >> 3;
                int kgs = (gid & 7) ^ (r & 7);
                gll16(dw1b + (size_t)((j + 1) * 128 + r) * 64 + kgs * 8,
                      Wd + buf * 8192 + chunk * 512);
            }
        }
        f32x4 acc[4][2] = {};
        const unsigned short* W = Wd + (j & 1) * 8192;
        #pragma unroll
        for (int s = 0; s < 2; ++s) {
            bf16x8 af[4], bf[2];
            #pragma unroll
            for (int mi = 0; mi < 4; ++mi) {
                int row = wr * 64 + mi * 16 + lr;
                int g = (s * 4 + kh) ^ (row & 7);
                af[mi] = *(const bf16x8*)(Pi + row * 64 + g * 8);
            }
            #pragma unroll
            for (int ni = 0; ni < 2; ++ni) {
                int row = wc * 32 + ni * 16 + lr;
                int g = (s * 4 + kh) ^ (row & 7);
                bf[ni] = *(const bf16x8*)(W + row * 64 + g * 8);
            }
            #pragma unroll
            for (int mi = 0; mi < 4; ++mi)
                #pragma unroll
                for (int ni = 0; ni < 2; ++ni)
                    acc[mi][ni] = __builtin_amdgcn_mfma_f32_16x16x32_bf16(
                        af[mi], bf[ni], acc[mi][ni], 0, 0, 0);
        }
        #pragma unroll
        for (int mi = 0; mi < 4; ++mi) {
            #pragma unroll
            for (int ni = 0; ni < 2; ++ni) {
                int gn = j * 128 + wc * 32 + ni * 16 + lr;
                float bs = biasd1[gn];
                #pragma unroll
                for (int jj = 0; jj < 4; ++jj) {
                    long gm = block_m + wr * 64 + mi * 16 + rg + jj;
                    float z = fmaxf(acc[mi][ni][jj] + bs, 0.f);
                    hdb[gm * 512 + gn] = bf16_bits(z);
                }
            }
        }
        __syncthreads();   // Wd[j&1] reads done + next tile landed
    }
}

// Merged weight preps + cast_x. blockIdx ranges:
//  [0,1664): w1b  [1664,1920): wab  [1920,2048): dw1b  [2048,3840): dw2b
//  [3840, 3840+13312): cast_x granule pass
__global__ __launch_bounds__(256) void prep_cast(
    const float* __restrict__ x, unsigned short* __restrict__ xb,
    const float* __restrict__ enc_w1, const float* __restrict__ enc_b1,
    const float* __restrict__ Wa, const float* __restrict__ ba,
    const float* __restrict__ Wb, const float* __restrict__ bb,
    const float* __restrict__ dec_w1, const float* __restrict__ dec_b1,
    const float* __restrict__ dec_w2, const float* __restrict__ dec_b2,
    unsigned short* __restrict__ w1b, float* __restrict__ bias1,
    unsigned short* __restrict__ wab, float* __restrict__ biasab,
    unsigned short* __restrict__ dw1b, float* __restrict__ biasd1,
    unsigned short* __restrict__ dw2b, float* __restrict__ biasd2)
{
    int bid = blockIdx.x;
    int t = threadIdx.x;
    if (bid >= 3840) {                   // cast_x: x f32 -> xb bf16 [B][832]
        int gid = (bid - 3840) * 256 + t;
        int r = gid / 104;
        int c = gid - r * 104;
        union { __bf16 b[8]; uint4 u4; } pk;
        if (c < 98) {
            const float4* p = (const float4*)(x + (size_t)r * 784 + c * 8);
            float4 f0 = p[0], f1 = p[1];
            pk.b[0] = (__bf16)f0.x; pk.b[1] = (__bf16)f0.y;
            pk.b[2] = (__bf16)f0.z; pk.b[3] = (__bf16)f0.w;
            pk.b[4] = (__bf16)f1.x; pk.b[5] = (__bf16)f1.y;
            pk.b[6] = (__bf16)f1.z; pk.b[7] = (__bf16)f1.w;
        } else {
            pk.u4 = make_uint4(0, 0, 0, 0);
        }
        *(uint4*)(xb + (size_t)r * 832 + c * 8) = pk.u4;
    } else if (bid < 1664) {             // w1b
        int idx = bid * 256 + t;
        int n = idx / 832, k = idx - n * 832;
        float v = (n < 500 && k < 784) ? enc_w1[(size_t)k * 500 + n] : 0.f;
        w1b[idx] = bf16_bits(v);
        if (k == 0) bias1[n] = (n < 500) ? enc_b1[n] : 0.f;
    } else if (bid < 1920) {             // wab
        int idx = (bid - 1664) * 256 + t;
        int n = idx >> 9, k = idx & 511;
        float v = 0.f;
        if (k < 500) {
            if (n < 50)       v = Wa[(size_t)k * 50 + n];
            else if (n < 100) v = Wb[(size_t)k * 50 + (n - 50)];
        }
        wab[idx] = bf16_bits(v);
        if (k == 0) biasab[n] = (n < 50) ? ba[n] : ((n < 100) ? bb[n - 50] : 0.f);
    } else if (bid < 2048) {             // dw1b
        int idx = (bid - 1920) * 256 + t;
        int n = idx >> 6, k = idx & 63;
        float v = (n < 500 && k < 50) ? dec_w1[(size_t)k * 500 + n] : 0.f;
        dw1b[idx] = bf16_bits(v);
        if (k == 0) biasd1[n] = (n < 500) ? dec_b1[n] : 0.f;
    } else {                             // dw2b
        int idx = (bid - 2048) * 256 + t;
        int n = idx >> 9, k = idx & 511;
        float v = (n < 784 && k < 500) ? dec_w2[(size_t)k * 784 + n] : 0.f;
        dw2b[idx] = bf16_bits(v);
        if (k == 0) biasd2[n] = (n < 784) ? dec_b2[n] : 0.f;
    }
}

extern "C" void kernel_launch(void* const* d_in, const int* in_sizes, int n_in,
                              void* d_out, int out_size, void* d_ws, size_t ws_size,
                              hipStream_t stream) {
    const float* x       = (const float*)d_in[0];
    const float* u       = (const float*)d_in[1];
    const float* enc_w1  = (const float*)d_in[2];
    const float* enc_b1  = (const float*)d_in[3];
    const float* w_alpha = (const float*)d_in[4];
    const float* b_alpha = (const float*)d_in[5];
    const float* w_beta  = (const float*)d_in[6];
    const float* b_beta  = (const float*)d_in[7];
    const float* dec_w1  = (const float*)d_in[8];
    const float* dec_b1  = (const float*)d_in[9];
    const float* dec_w2  = (const float*)d_in[10];
    const float* dec_b2  = (const float*)d_in[11];

    const int D = 784;

    float* out   = (float*)d_out;
    float* recon = out;                              // [B,784] f32
    float* alpha = out + (size_t)BATCH * D;          // [B,50]; beta at +B*50

    unsigned short* xb = (unsigned short*)d_out;     // [B][832] bf16, dead til GEMM5

    char* ws = (char*)d_ws;
    unsigned short* w1b  = (unsigned short*)(ws);             // 512*832*2
    unsigned short* wab  = (unsigned short*)(ws + 851968);    // 128*512*2
    unsigned short* dw1b = (unsigned short*)(ws + 983040);    // 512*64*2
    unsigned short* dw2b = (unsigned short*)(ws + 1048576);   // 896*512*2
    float* bias1  = (float*)(ws + 1966080);
    float* biasab = (float*)(ws + 1968128);
    float* biasd1 = (float*)(ws + 1970688);
    float* biasd2 = (float*)(ws + 1972736);
    unsigned short* h    = (unsigned short*)(ws + 2097152);   // [B][512] bf16
    unsigned short* hdb  = h;                                  // per-block phase-safe alias

    // ---- prep + cast (one launch) ----
    prep_cast<<<dim3(3840 + BATCH * 104 / 256), 256, 0, stream>>>(
        x, xb, enc_w1, enc_b1, w_alpha, b_alpha, w_beta, b_beta,
        dec_w1, dec_b1, dec_w2, dec_b2,
        w1b, bias1, wab, biasab, dw1b, biasd1, dw2b, biasd2);

    // ---- GEMM1: h = relu(xb @ enc_w1 + b1) ----
    mfma_gemm<0><<<dim3((512 / BN) * (BATCH / BM)), NTHR, 0, stream>>>(
        xb, w1b, bias1, h, 832, 832, 512, 500, 512 / BN);

    // ---- mid_fused: alpha/beta + sample + GEMM4 ----
    mid_fused<<<dim3(BATCH / 128), NTHR, 0, stream>>>(
        h, wab, biasab, u, dw1b, biasd1, alpha, hdb);

    // ---- GEMM5: recon = sigmoid(hd @ dec_w2 + b) (overwrites xb) ----
    mfma_gemm<2><<<dim3((896 / BN) * (BATCH / BM)), NTHR, 0, stream>>>(
        hdb, dw2b, biasd2, recon, 512, 512, 784, 784, 896 / BN);
}

// Round 16
// 144.585 us; speedup vs baseline: 1.8032x; 1.0033x over previous
//
#include <hip/hip_runtime.h>
#include <math.h>

// StickBreakingVAE forward, all-bf16 MFMA, 8-wave blocks, XCD swizzle.
// r16: mid_fused LDS 112->80 KB (ab stored bf16) -> 2 blocks/CU for P1 overlap.
// Kernels: prep_cast, GEMM1, mid_fused, GEMM5.
//  mid_fused (grid 256, 80KB LDS): per 128-row block
//    P1: [alpha|beta] pre-act = h @ wab (K=512, 2-barrier gll loop)
//    P2: softplus -> d_out alpha/beta (f32 exact) AND LDS ab bf16
//    P3: sample (a,b from LDS bf16, u reg-hoisted) -> Pi LDS (swizzled)
//    P4: hd = relu(pi @ dec_w1 + b) (dbuf'd 4-tile n-loop)
// B=32768, D=784, H=500, K=50.

typedef __bf16 bf16x8 __attribute__((ext_vector_type(8)));
typedef float f32x4 __attribute__((ext_vector_type(4)));

#define BATCH 32768
#define BM 128
#define BN 128
#define BK 64
#define NTHR 512

__device__ __forceinline__ unsigned short bf16_bits(float f) {
    __bf16 b = (__bf16)f;
    return __builtin_bit_cast(unsigned short, b);
}

__device__ __forceinline__ float f32_from_bf16(unsigned short s) {
    unsigned int ui = ((unsigned int)s) << 16;
    return __builtin_bit_cast(float, ui);
}

__device__ __forceinline__ void gll16(const void* src, void* ldsdst) {
    __builtin_amdgcn_global_load_lds(
        (const __attribute__((address_space(1))) unsigned int*)src,
        (__attribute__((address_space(3))) unsigned int*)ldsdst,
        16, 0, 0);
}

// chunked bijective XCD swizzle (T1, m204)
__device__ __forceinline__ int xcd_swz(int orig, int nwg) {
    int q = nwg >> 3, r8 = nwg & 7;
    int xcd = orig & 7;
    int chunkbase = (xcd < r8) ? xcd * (q + 1) : r8 * (q + 1) + (xcd - r8) * q;
    return chunkbase + (orig >> 3);
}

// MODE 0: relu -> bf16 C [ldc]; MODE 2: sigmoid -> f32 C [B,Nreal] masked.
template<int MODE>
__global__ __launch_bounds__(NTHR, 4) void mfma_gemm(
    const unsigned short* __restrict__ A,   // [M][lda] bf16 (zero-padded)
    const unsigned short* __restrict__ Bt,  // [Npad][Kpad] bf16 (zero-padded)
    const float* __restrict__ bias,         // [Npad]
    void* __restrict__ Cv,
    int Kpad, int lda, int ldc, int Nreal, int nbx)
{
    __shared__ unsigned short As[BM * BK];
    __shared__ unsigned short Bs[BN * BK];

    const int wgid = xcd_swz(blockIdx.x, gridDim.x);
    const int bn = wgid % nbx;
    const size_t block_m = (size_t)(wgid / nbx) * BM;
    const int block_n = bn * BN;

    const int tid = threadIdx.x;
    const int l = tid & 63;
    const int wid = tid >> 6;
    const int wr = wid >> 2, wc = wid & 3;   // wave tile 64x32
    const int lr = l & 15;
    const int kh = l >> 4;

    f32x4 acc[4][2] = {};

    for (int k0 = 0; k0 < Kpad; k0 += BK) {
        #pragma unroll
        for (int i = 0; i < 2; ++i) {
            int chunk = wid * 2 + i;
            int gid = chunk * 64 + l;
            int r = gid >> 3;
            int kgs = (gid & 7) ^ (r & 7);
            gll16(Bt + (size_t)(block_n + r) * Kpad + k0 + kgs * 8, Bs + chunk * 512);
        }
        #pragma unroll
        for (int i = 0; i < 2; ++i) {
            int chunk = wid * 2 + i;
            int gid = chunk * 64 + l;
            int r = gid >> 3;
            int kgs = (gid & 7) ^ (r & 7);
            gll16(A + (block_m + r) * (size_t)lda + k0 + kgs * 8, As + chunk * 512);
        }
        __syncthreads();
        #pragma unroll
        for (int s = 0; s < 2; ++s) {
            bf16x8 af[4], bf[2];
            #pragma unroll
            for (int mi = 0; mi < 4; ++mi) {
                int row = wr * 64 + mi * 16 + lr;
                int g = (s * 4 + kh) ^ (row & 7);
                af[mi] = *(const bf16x8*)(As + row * 64 + g * 8);
            }
            #pragma unroll
            for (int ni = 0; ni < 2; ++ni) {
                int row = wc * 32 + ni * 16 + lr;
                int g = (s * 4 + kh) ^ (row & 7);
                bf[ni] = *(const bf16x8*)(Bs + row * 64 + g * 8);
            }
            #pragma unroll
            for (int mi = 0; mi < 4; ++mi)
                #pragma unroll
                for (int ni = 0; ni < 2; ++ni)
                    acc[mi][ni] = __builtin_amdgcn_mfma_f32_16x16x32_bf16(
                        af[mi], bf[ni], acc[mi][ni], 0, 0, 0);
        }
        __syncthreads();
    }

    const int rg = (l >> 4) * 4;
    #pragma unroll
    for (int mi = 0; mi < 4; ++mi) {
        #pragma unroll
        for (int ni = 0; ni < 2; ++ni) {
            int gn = block_n + wc * 32 + ni * 16 + lr;
            float bs = bias[gn];
            #pragma unroll
            for (int j = 0; j < 4; ++j) {
                long gm = block_m + wr * 64 + mi * 16 + rg + j;
                float z = acc[mi][ni][j] + bs;
                if (MODE == 0) {
                    z = fmaxf(z, 0.f);
                    ((unsigned short*)Cv)[gm * ldc + gn] = bf16_bits(z);
                } else {
                    if (gn < Nreal) {
                        z = __fdividef(1.f, 1.f + __expf(-z));
                        ((float*)Cv)[gm * Nreal + gn] = z;
                    }
                }
            }
        }
    }
}

// Fused GEMM2/3 + softplus + sample + GEMM4. Grid 256 x 512thr, 80KB LDS.
__global__ __launch_bounds__(NTHR, 2) void mid_fused(
    const unsigned short* __restrict__ h,      // [B][512] bf16
    const unsigned short* __restrict__ wab,    // [128][512] bf16
    const float* __restrict__ biasab,          // [128]
    const float* __restrict__ u,               // [B][50] f32
    const unsigned short* __restrict__ dw1b,   // [512][64] bf16
    const float* __restrict__ biasd1,          // [512]
    float* __restrict__ outAB,                 // alpha base (d_out + B*784)
    unsigned short* __restrict__ hdb)          // [B][512] bf16 (aliases h)
{
    __shared__ __align__(16) unsigned char smem[81920];   // 80 KB -> 2 blocks/CU
    unsigned short* abh = (unsigned short*)smem;          // [2][128][64] bf16, 32KB
    unsigned short* Pi  = (unsigned short*)(smem + 32768);       // [128][64], 16KB
    unsigned short* Wd  = (unsigned short*)(smem + 49152);       // [2][128][64], 32KB
    unsigned short* As  = (unsigned short*)(smem + 49152);       // P1 alias of Wd
    unsigned short* Bs  = (unsigned short*)(smem + 65536);

    const int tid = threadIdx.x;
    const int l = tid & 63;
    const int wid = tid >> 6;
    const int wr = wid >> 2, wc = wid & 3;
    const int lr = l & 15;
    const int kh = l >> 4;
    const int rg = (l >> 4) * 4;

    const int wgid = xcd_swz(blockIdx.x, gridDim.x);
    const size_t block_m = (size_t)wgid * 128;

    // ---- P1: alpha/beta pre-act = h @ wab, K=512 ----
    {
        f32x4 acc[4][2] = {};
        for (int k0 = 0; k0 < 512; k0 += BK) {
            #pragma unroll
            for (int i = 0; i < 2; ++i) {
                int chunk = wid * 2 + i;
                int gid = chunk * 64 + l;
                int r = gid >> 3;
                int kgs = (gid & 7) ^ (r & 7);
                gll16(wab + (size_t)r * 512 + k0 + kgs * 8, Bs + chunk * 512);
            }
            #pragma unroll
            for (int i = 0; i < 2; ++i) {
                int chunk = wid * 2 + i;
                int gid = chunk * 64 + l;
                int r = gid >> 3;
                int kgs = (gid & 7) ^ (r & 7);
                gll16(h + (block_m + r) * 512 + k0 + kgs * 8, As + chunk * 512);
            }
            __syncthreads();
            #pragma unroll
            for (int s = 0; s < 2; ++s) {
                bf16x8 af[4], bf[2];
                #pragma unroll
                for (int mi = 0; mi < 4; ++mi) {
                    int row = wr * 64 + mi * 16 + lr;
                    int g = (s * 4 + kh) ^ (row & 7);
                    af[mi] = *(const bf16x8*)(As + row * 64 + g * 8);
                }
                #pragma unroll
                for (int ni = 0; ni < 2; ++ni) {
                    int row = wc * 32 + ni * 16 + lr;
                    int g = (s * 4 + kh) ^ (row & 7);
                    bf[ni] = *(const bf16x8*)(Bs + row * 64 + g * 8);
                }
                #pragma unroll
                for (int mi = 0; mi < 4; ++mi)
                    #pragma unroll
                    for (int ni = 0; ni < 2; ++ni)
                        acc[mi][ni] = __builtin_amdgcn_mfma_f32_16x16x32_bf16(
                            af[mi], bf[ni], acc[mi][ni], 0, 0, 0);
            }
            __syncthreads();   // last iter: As/Bs reads done -> Wd region reusable
        }

        // ---- stage dec_w1 tile 0 early (lands during P2/P3) ----
        #pragma unroll
        for (int i = 0; i < 2; ++i) {
            int chunk = wid * 2 + i;
            int gid = chunk * 64 + l;
            int r = gid >> 3;
            int kgs = (gid & 7) ^ (r & 7);
            gll16(dw1b + (size_t)r * 64 + kgs * 8, Wd + chunk * 512);
        }

        // ---- P2: softplus -> d_out (f32 exact) + LDS ab (bf16) ----
        #pragma unroll
        for (int mi = 0; mi < 4; ++mi) {
            #pragma unroll
            for (int ni = 0; ni < 2; ++ni) {
                int gn = wc * 32 + ni * 16 + lr;       // 0..127
                float bs = biasab[gn];
                #pragma unroll
                for (int j = 0; j < 4; ++j) {
                    int lm = wr * 64 + mi * 16 + rg + j;
                    long gm = block_m + lm;
                    float z = acc[mi][ni][j] + bs;
                    z = (z > 0.f) ? z + __logf(1.f + __expf(-z))
                                  : __logf(1.f + __expf(z));
                    if (gn < 50) {
                        outAB[gm * 50 + gn] = z;
                        abh[lm * 64 + gn] = bf16_bits(z);               // alpha
                    } else if (gn < 100) {
                        outAB[(size_t)BATCH * 50 + gm * 50 + (gn - 50)] = z;
                        abh[8192 + lm * 64 + (gn - 50)] = bf16_bits(z); // beta
                    }
                }
            }
        }
    }

    // ---- P3: sample. u hoisted to regs BEFORE barrier; a,b from LDS bf16 ----
    float ur[16];
    #pragma unroll
    for (int rr = 0; rr < 16; ++rr) {
        size_t grow = block_m + wid * 16 + rr;
        ur[rr] = (l < 50) ? u[grow * 50 + l] : 0.5f;
    }
    __syncthreads();   // abh visible (drains vmcnt too; Wd tile0 landed)

    #pragma unroll
    for (int rr = 0; rr < 16; ++rr) {
        int row = wid * 16 + rr;
        float v = 0.f, w = 1.f;
        if (l < 50) {
            float a = f32_from_bf16(abh[row * 64 + l]);
            float b = f32_from_bf16(abh[8192 + row * 64 + l]);
            float t = exp2f(__fdividef(log2f(ur[rr]), b));      // u^(1/beta)
            v = exp2f(__fdividef(log2f(1.f - t), a));           // (1-t)^(1/alpha)
            w = 1.f - v;
        }
        float p = w;
        #pragma unroll
        for (int off = 1; off < 64; off <<= 1) {
            float t2 = __shfl_up(p, off, 64);
            if (l >= off) p *= t2;
        }
        float ex = __shfl_up(p, 1, 64);
        if (l == 0) ex = 1.f;
        float pi = (l < 50) ? v * ex : 0.f;
        Pi[row * 64 + (((l >> 3) ^ (row & 7)) << 3) + (l & 7)] = bf16_bits(pi);
    }
    __syncthreads();   // Pi ready

    // ---- P4: hd = relu(pi @ dec_w1 + b), 4 n-tiles, Wd dbuf ----
    for (int j = 0; j < 4; ++j) {
        if (j < 3) {
            int buf = (j + 1) & 1;
            #pragma unroll
            for (int i = 0; i < 2; ++i) {
                int chunk = wid * 2 + i;
                int gid = chunk * 64 + l;
                int r = gid >> 3;
                int kgs = (gid & 7) ^ (r & 7);
                gll16(dw1b + (size_t)((j + 1) * 128 + r) * 64 + kgs * 8,
                      Wd + buf * 8192 + chunk * 512);
            }
        }
        f32x4 acc[4][2] = {};
        const unsigned short* W = Wd + (j & 1) * 8192;
        #pragma unroll
        for (int s = 0; s < 2; ++s) {
            bf16x8 af[4], bf[2];
            #pragma unroll
            for (int mi = 0; mi < 4; ++mi) {
                int row = wr * 64 + mi * 16 + lr;
                int g = (s * 4 + kh) ^ (row & 7);
                af[mi] = *(const bf16x8*)(Pi + row * 64 + g * 8);
            }
            #pragma unroll
            for (int ni = 0; ni < 2; ++ni) {
                int row = wc * 32 + ni * 16 + lr;
                int g = (s * 4 + kh) ^ (row & 7);
                bf[ni] = *(const bf16x8*)(W + row * 64 + g * 8);
            }
            #pragma unroll
            for (int mi = 0; mi < 4; ++mi)
                #pragma unroll
                for (int ni = 0; ni < 2; ++ni)
                    acc[mi][ni] = __builtin_amdgcn_mfma_f32_16x16x32_bf16(
                        af[mi], bf[ni], acc[mi][ni], 0, 0, 0);
        }
        #pragma unroll
        for (int mi = 0; mi < 4; ++mi) {
            #pragma unroll
            for (int ni = 0; ni < 2; ++ni) {
                int gn = j * 128 + wc * 32 + ni * 16 + lr;
                float bs = biasd1[gn];
                #pragma unroll
                for (int jj = 0; jj < 4; ++jj) {
                    long gm = block_m + wr * 64 + mi * 16 + rg + jj;
                    float z = fmaxf(acc[mi][ni][jj] + bs, 0.f);
                    hdb[gm * 512 + gn] = bf16_bits(z);
                }
            }
        }
        __syncthreads();   // Wd[j&1] reads done + next tile landed
    }
}

// Merged weight preps + cast_x. blockIdx ranges:
//  [0,1664): w1b  [1664,1920): wab  [1920,2048): dw1b  [2048,3840): dw2b
//  [3840, 3840+13312): cast_x granule pass
__global__ __launch_bounds__(256) void prep_cast(
    const float* __restrict__ x, unsigned short* __restrict__ xb,
    const float* __restrict__ enc_w1, const float* __restrict__ enc_b1,
    const float* __restrict__ Wa, const float* __restrict__ ba,
    const float* __restrict__ Wb, const float* __restrict__ bb,
    const float* __restrict__ dec_w1, const float* __restrict__ dec_b1,
    const float* __restrict__ dec_w2, const float* __restrict__ dec_b2,
    unsigned short* __restrict__ w1b, float* __restrict__ bias1,
    unsigned short* __restrict__ wab, float* __restrict__ biasab,
    unsigned short* __restrict__ dw1b, float* __restrict__ biasd1,
    unsigned short* __restrict__ dw2b, float* __restrict__ biasd2)
{
    int bid = blockIdx.x;
    int t = threadIdx.x;
    if (bid >= 3840) {                   // cast_x: x f32 -> xb bf16 [B][832]
        int gid = (bid - 3840) * 256 + t;
        int r = gid / 104;
        int c = gid - r * 104;
        union { __bf16 b[8]; uint4 u4; } pk;
        if (c < 98) {
            const float4* p = (const float4*)(x + (size_t)r * 784 + c * 8);
            float4 f0 = p[0], f1 = p[1];
            pk.b[0] = (__bf16)f0.x; pk.b[1] = (__bf16)f0.y;
            pk.b[2] = (__bf16)f0.z; pk.b[3] = (__bf16)f0.w;
            pk.b[4] = (__bf16)f1.x; pk.b[5] = (__bf16)f1.y;
            pk.b[6] = (__bf16)f1.z; pk.b[7] = (__bf16)f1.w;
        } else {
            pk.u4 = make_uint4(0, 0, 0, 0);
        }
        *(uint4*)(xb + (size_t)r * 832 + c * 8) = pk.u4;
    } else if (bid < 1664) {             // w1b
        int idx = bid * 256 + t;
        int n = idx / 832, k = idx - n * 832;
        float v = (n < 500 && k < 784) ? enc_w1[(size_t)k * 500 + n] : 0.f;
        w1b[idx] = bf16_bits(v);
        if (k == 0) bias1[n] = (n < 500) ? enc_b1[n] : 0.f;
    } else if (bid < 1920) {             // wab
        int idx = (bid - 1664) * 256 + t;
        int n = idx >> 9, k = idx & 511;
        float v = 0.f;
        if (k < 500) {
            if (n < 50)       v = Wa[(size_t)k * 50 + n];
            else if (n < 100) v = Wb[(size_t)k * 50 + (n - 50)];
        }
        wab[idx] = bf16_bits(v);
        if (k == 0) biasab[n] = (n < 50) ? ba[n] : ((n < 100) ? bb[n - 50] : 0.f);
    } else if (bid < 2048) {             // dw1b
        int idx = (bid - 1920) * 256 + t;
        int n = idx >> 6, k = idx & 63;
        float v = (n < 500 && k < 50) ? dec_w1[(size_t)k * 500 + n] : 0.f;
        dw1b[idx] = bf16_bits(v);
        if (k == 0) biasd1[n] = (n < 500) ? dec_b1[n] : 0.f;
    } else {                             // dw2b
        int idx = (bid - 2048) * 256 + t;
        int n = idx >> 9, k = idx & 511;
        float v = (n < 784 && k < 500) ? dec_w2[(size_t)k * 784 + n] : 0.f;
        dw2b[idx] = bf16_bits(v);
        if (k == 0) biasd2[n] = (n < 784) ? dec_b2[n] : 0.f;
    }
}

extern "C" void kernel_launch(void* const* d_in, const int* in_sizes, int n_in,
                              void* d_out, int out_size, void* d_ws, size_t ws_size,
                              hipStream_t stream) {
    const float* x       = (const float*)d_in[0];
    const float* u       = (const float*)d_in[1];
    const float* enc_w1  = (const float*)d_in[2];
    const float* enc_b1  = (const float*)d_in[3];
    const float* w_alpha = (const float*)d_in[4];
    const float* b_alpha = (const float*)d_in[5];
    const float* w_beta  = (const float*)d_in[6];
    const float* b_beta  = (const float*)d_in[7];
    const float* dec_w1  = (const float*)d_in[8];
    const float* dec_b1  = (const float*)d_in[9];
    const float* dec_w2  = (const float*)d_in[10];
    const float* dec_b2  = (const float*)d_in[11];

    const int D = 784;

    float* out   = (float*)d_out;
    float* recon = out;                              // [B,784] f32
    float* alpha = out + (size_t)BATCH * D;          // [B,50]; beta at +B*50

    unsigned short* xb = (unsigned short*)d_out;     // [B][832] bf16, dead til GEMM5

    char* ws = (char*)d_ws;
    unsigned short* w1b  = (unsigned short*)(ws);             // 512*832*2
    unsigned short* wab  = (unsigned short*)(ws + 851968);    // 128*512*2
    unsigned short* dw1b = (unsigned short*)(ws + 983040);    // 512*64*2
    unsigned short* dw2b = (unsigned short*)(ws + 1048576);   // 896*512*2
    float* bias1  = (float*)(ws + 1966080);
    float* biasab = (float*)(ws + 1968128);
    float* biasd1 = (float*)(ws + 1970688);
    float* biasd2 = (float*)(ws + 1972736);
    unsigned short* h    = (unsigned short*)(ws + 2097152);   // [B][512] bf16
    unsigned short* hdb  = h;                                  // per-block phase-safe alias

    // ---- prep + cast (one launch) ----
    prep_cast<<<dim3(3840 + BATCH * 104 / 256), 256, 0, stream>>>(
        x, xb, enc_w1, enc_b1, w_alpha, b_alpha, w_beta, b_beta,
        dec_w1, dec_b1, dec_w2, dec_b2,
        w1b, bias1, wab, biasab, dw1b, biasd1, dw2b, biasd2);

    // ---- GEMM1: h = relu(xb @ enc_w1 + b1) ----
    mfma_gemm<0><<<dim3((512 / BN) * (BATCH / BM)), NTHR, 0, stream>>>(
        xb, w1b, bias1, h, 832, 832, 512, 500, 512 / BN);

    // ---- mid_fused: alpha/beta + sample + GEMM4 ----
    mid_fused<<<dim3(BATCH / 128), NTHR, 0, stream>>>(
        h, wab, biasab, u, dw1b, biasd1, alpha, hdb);

    // ---- GEMM5: recon = sigmoid(hd @ dec_w2 + b) (overwrites xb) ----
    mfma_gemm<2><<<dim3((896 / BN) * (BATCH / BM)), NTHR, 0, stream>>>(
        hdb, dw2b, biasd2, recon, 512, 512, 784, 784, 896 / BN);
}